// Round 16
// baseline (361.350 us; speedup 1.0000x reference)
//
#include <hip/hip_runtime.h>
#include <math.h>

typedef unsigned short ushort_t;
typedef __attribute__((ext_vector_type(8))) short short8;
typedef __attribute__((ext_vector_type(4))) float f32x4;

__device__ inline unsigned bfpair(float lo, float hi) {
  unsigned r;
  asm("v_cvt_pk_bf16_f32 %0, %1, %2" : "=v"(r) : "v"(lo), "v"(hi));
  return r;
}
__device__ inline ushort_t bf16of(float v) { return (ushort_t)(bfpair(v, v) & 0xffffu); }
__device__ inline void permswap32(unsigned &a, unsigned &b) {
  asm("v_permlane32_swap_b32 %0, %1" : "+v"(a), "+v"(b));
}
__device__ inline void permswap16(unsigned &a, unsigned &b) {
  asm("v_permlane16_swap_b32 %0, %1" : "+v"(a), "+v"(b));
}

// ---------------- fused prep (R11-verified) ----------------
__device__ void transpose_tile(const float* __restrict__ W, ushort_t* __restrict__ Wt,
                               int K, int N, int bx, int by, int t)
{
  __shared__ float Ls[32][33];
  const int n0 = bx * 32, k0 = by * 32;
  const int tx = t & 31, tyb = t >> 5;
  #pragma unroll
  for (int s = 0; s < 4; ++s) {
    const int k = tyb + s * 8;
    Ls[k][tx] = W[(size_t)(k0 + k) * N + n0 + tx];
  }
  __syncthreads();
  #pragma unroll
  for (int s = 0; s < 2; ++s) {
    const int idx = t + 256 * s;
    const int n = idx >> 4, kk = (idx & 15) * 2;
    const unsigned pk = bfpair(Ls[kk][n], Ls[kk + 1][n]);
    *(unsigned*)&Wt[(size_t)(n0 + n) * K + k0 + kk] = pk;
  }
}

__global__ __launch_bounds__(256) void prep_all_k(
    const float* __restrict__ W1, ushort_t* __restrict__ W1t,
    const float* __restrict__ W2, ushort_t* __restrict__ W2t,
    const float* __restrict__ W3, ushort_t* __restrict__ W3t,
    const float* __restrict__ Wa1, ushort_t* __restrict__ Wa1t,
    const float* __restrict__ Wq, const float* __restrict__ Wk,
    const float* __restrict__ Wv, ushort_t* __restrict__ WqkvT)
{
  const int bid = blockIdx.x;
  const int t = threadIdx.x;
  if (bid < 256)      { transpose_tile(W1, W1t, 1024, 256, bid & 7, bid >> 3, t); }
  else if (bid < 288) { const int l = bid - 256; transpose_tile(W2, W2t, 256, 128, l & 3, l >> 2, t); }
  else if (bid < 296) { const int l = bid - 288; transpose_tile(W3, W3t, 128,  64, l & 1, l >> 1, t); }
  else if (bid < 300) { const int l = bid - 296; transpose_tile(Wa1, Wa1t, 64,  64, l & 1, l >> 1, t); }
  else {
    for (int e = t; e < 80 * 64; e += 256) {
      const int j = e >> 6, k = e & 63;
      float v;
      if (j < 8)       v = Wq[k * 8 + j];
      else if (j < 16) v = Wk[k * 8 + (j - 8)];
      else             v = Wv[k * 64 + (j - 16)];
      WqkvT[e] = bf16of(v);
    }
  }
}

// ---------------- LDS-staged pipelined bf16 MFMA GEMM (R9-verified; REP for profiling) ----------------
template<int K, int N, int WAVES, bool A_FP32, int OMODE, int REP>
__global__ __launch_bounds__(WAVES * 64) void gemm_staged(
    const void* __restrict__ Ap, const ushort_t* __restrict__ Wt,
    const float* __restrict__ bias, void* __restrict__ C0, void* __restrict__ C1)
{
  constexpr int BM = 32;
  constexpr int NWN = N / 32;
  constexpr int NK = K / 32;
  constexpr int A_CH = BM * 4;
  constexpr int B_CH = N * 4;
  static_assert(WAVES * 64 == B_CH, "threads must equal B chunk count");
  static_assert(A_CH <= WAVES * 64, "");

  const int tid = threadIdx.x;
  const int wave = tid >> 6, lane = tid & 63;
  const int ln = lane & 15, g = lane >> 4;
  const int wm = wave / NWN, wn = wave % NWN;
  const int bm0 = blockIdx.x * BM;

  __shared__ ushort_t Als[2][BM][40];
  __shared__ ushort_t Bls[2][N][40];

  const float* Af = (const float*)Ap;
  const ushort_t* Ab = (const ushort_t*)Ap;

  const bool hasA = (tid < A_CH);
  const int arow = tid >> 2, akq = tid & 3;
  const int bc = hasA ? (B_CH - A_CH + tid) : (tid - A_CH);
  const int brow = bc >> 2, bkq = bc & 3;

  float4 rf0, rf1;
  short8 ra, rb;

  auto LOADK = [&](int ks) {
    const int k0 = ks * 32;
    if (hasA) {
      if (A_FP32) {
        const float* src = &Af[(size_t)(bm0 + arow) * K + k0 + akq * 8];
        rf0 = *(const float4*)src;
        rf1 = *(const float4*)(src + 4);
      } else {
        ra = *(const short8*)&Ab[(size_t)(bm0 + arow) * K + k0 + akq * 8];
      }
    }
    rb = *(const short8*)&Wt[(size_t)brow * K + k0 + bkq * 8];
  };
  auto WRITEK = [&](int cur) {
    if (hasA) {
      short8 wa;
      if (A_FP32) {
        union { unsigned u[4]; short8 s8; } cv;
        cv.u[0] = bfpair(rf0.x, rf0.y);
        cv.u[1] = bfpair(rf0.z, rf0.w);
        cv.u[2] = bfpair(rf1.x, rf1.y);
        cv.u[3] = bfpair(rf1.z, rf1.w);
        wa = cv.s8;
      } else {
        wa = ra;
      }
      *(short8*)&Als[cur][arow][akq * 8] = wa;
    }
    *(short8*)&Bls[cur][brow][bkq * 8] = rb;
  };

  f32x4 acc0, acc1;
  #pragma unroll 1
  for (int rep = 0; rep < REP; ++rep) {
    acc0 = (f32x4){0.f, 0.f, 0.f, 0.f};
    acc1 = (f32x4){0.f, 0.f, 0.f, 0.f};
    __syncthreads();
    LOADK(0);
    int cur = 0;
    for (int ks = 0; ks < NK; ++ks) {
      WRITEK(cur);
      __syncthreads();
      if (ks + 1 < NK) LOADK(ks + 1);
      const short8 af = *(const short8*)&Als[cur][wm * 16 + ln][g * 8];
      const short8 b0 = *(const short8*)&Bls[cur][wn * 32 + ln][g * 8];
      const short8 b1 = *(const short8*)&Bls[cur][wn * 32 + 16 + ln][g * 8];
      acc0 = __builtin_amdgcn_mfma_f32_16x16x32_bf16(af, b0, acc0, 0, 0, 0);
      acc1 = __builtin_amdgcn_mfma_f32_16x16x32_bf16(af, b1, acc1, 0, 0, 0);
      cur ^= 1;
    }
  }

  #pragma unroll
  for (int nt = 0; nt < 2; ++nt) {
    const f32x4 a = nt ? acc1 : acc0;
    #pragma unroll
    for (int r = 0; r < 4; ++r) {
      const int m = bm0 + wm * 16 + 4 * g + r;
      const int n = wn * 32 + nt * 16 + ln;
      float v = a[r] + bias[n];
      v = fmaxf(v, 0.f);
      if (OMODE == 0) {
        ((ushort_t*)C0)[(size_t)m * N + n] = bf16of(v);
      } else {
        ((float*)C0)[(size_t)m * N + n] = v;
      }
    }
  }
}

// ---------------- fused gemm2 + gemm3 + QKV (R12-verified; REP for profiling) ----------------
template<int REP>
__global__ __launch_bounds__(256) void mlp23_qkv_k(
    const ushort_t* __restrict__ H1b, const ushort_t* __restrict__ W2t,
    const float* __restrict__ b2, const ushort_t* __restrict__ W3t,
    const float* __restrict__ b3, const ushort_t* __restrict__ WqkvT,
    const float* __restrict__ bq, const float* __restrict__ bk, const float* __restrict__ bv,
    float* __restrict__ H3, ushort_t* __restrict__ Qb, ushort_t* __restrict__ Kb,
    ushort_t* __restrict__ VT)
{
  const int wave = threadIdx.x >> 6, lane = threadIdx.x & 63;
  const int ln = lane & 15, g = lane >> 4;
  const int q0 = blockIdx.x * 16;
  const f32x4 zero4 = {0.f, 0.f, 0.f, 0.f};

  __shared__ ushort_t H2ls[16][136];
  __shared__ ushort_t Hls[16][72];

  #pragma unroll 1
  for (int rep = 0; rep < REP; ++rep) {
    __syncthreads();
    f32x4 a2[2] = {zero4, zero4};
    #pragma unroll 2
    for (int k0 = 0; k0 < 256; k0 += 32) {
      const short8 af = *(const short8*)&H1b[(size_t)(q0 + ln) * 256 + k0 + g * 8];
      const short8 b0 = *(const short8*)&W2t[(size_t)(wave * 32 + ln) * 256 + k0 + g * 8];
      const short8 b1 = *(const short8*)&W2t[(size_t)(wave * 32 + 16 + ln) * 256 + k0 + g * 8];
      a2[0] = __builtin_amdgcn_mfma_f32_16x16x32_bf16(af, b0, a2[0], 0, 0, 0);
      a2[1] = __builtin_amdgcn_mfma_f32_16x16x32_bf16(af, b1, a2[1], 0, 0, 0);
    }
    #pragma unroll
    for (int nt = 0; nt < 2; ++nt)
      #pragma unroll
      for (int r = 0; r < 4; ++r) {
        const int n = wave * 32 + nt * 16 + ln;
        H2ls[4 * g + r][n] = bf16of(fmaxf(a2[nt][r] + b2[n], 0.f));
      }
    __syncthreads();

    f32x4 a3 = zero4;
    #pragma unroll
    for (int k0 = 0; k0 < 128; k0 += 32) {
      const short8 af = *(const short8*)&H2ls[ln][k0 + g * 8];
      const short8 bfr = *(const short8*)&W3t[(size_t)(wave * 16 + ln) * 128 + k0 + g * 8];
      a3 = __builtin_amdgcn_mfma_f32_16x16x32_bf16(af, bfr, a3, 0, 0, 0);
    }
    #pragma unroll
    for (int r = 0; r < 4; ++r) {
      const int m = q0 + 4 * g + r;
      const int n = wave * 16 + ln;
      float v = fmaxf(a3[r] + b3[n], 0.f);
      H3[(size_t)m * 64 + n] = v;
      Hls[4 * g + r][n] = bf16of(v);
    }
    __syncthreads();

    const int ntA = (wave == 0) ? 0 : (wave + 1);
    f32x4 accA = zero4, accB = zero4;
    #pragma unroll
    for (int k0 = 0; k0 < 64; k0 += 32) {
      const short8 af = *(const short8*)&Hls[ln][k0 + g * 8];
      const short8 bA = *(const short8*)&WqkvT[(size_t)(ntA * 16 + ln) * 64 + k0 + g * 8];
      accA = __builtin_amdgcn_mfma_f32_16x16x32_bf16(af, bA, accA, 0, 0, 0);
      if (wave == 0) {
        const short8 bB = *(const short8*)&WqkvT[(size_t)(16 + ln) * 64 + k0 + g * 8];
        accB = __builtin_amdgcn_mfma_f32_16x16x32_bf16(af, bB, accB, 0, 0, 0);
      }
    }
    if (wave == 0) {
      const float b0 = (ln < 8) ? bq[ln] : bk[ln - 8];
      #pragma unroll
      for (int r = 0; r < 4; ++r) {
        const int m = q0 + 4 * g + r;
        const float v = accA[r] + b0;
        if (ln < 8) Qb[(size_t)m * 8 + ln] = bf16of(v);
        else        Kb[(size_t)m * 8 + (ln - 8)] = bf16of(v);
      }
      const int d = ln;
      const float bb = bv[d];
      uint2 o;
      o.x = bfpair(accB[0] + bb, accB[1] + bb);
      o.y = bfpair(accB[2] + bb, accB[3] + bb);
      *(uint2*)&VT[(size_t)d * 8192 + q0 + 4 * g] = o;
    } else {
      const int d = (ntA - 1) * 16 + ln;
      const float bb = bv[d];
      uint2 o;
      o.x = bfpair(accA[0] + bb, accA[1] + bb);
      o.y = bfpair(accA[2] + bb, accA[3] + bb);
      *(uint2*)&VT[(size_t)d * 8192 + q0 + 4 * g] = o;
    }
  }
}

// ---------------- attention pass 1 (R15 structure; REP for profiling) ----------------
template<int REP>
__global__ __launch_bounds__(1024) void attn_part_k(
    const ushort_t* __restrict__ Qb, const ushort_t* __restrict__ Kb,
    const ushort_t* __restrict__ VT, float* __restrict__ Pnum,
    float* __restrict__ Pden)
{
  const int tid = threadIdx.x;
  const int wave = tid >> 6, lane = tid & 63;
  const int m = lane & 15, g = lane >> 4;
  const int qg = blockIdx.x & 31, js = blockIdx.x >> 5;
  const int q0 = qg * 256 + wave * 16;
  const int j0 = js * 1024;
  const f32x4 zero4 = {0.f,0.f,0.f,0.f};

  __shared__ ushort_t Vls[2][64][136];
  __shared__ ushort_t Kls[2][128][12];

  const int vd = tid >> 4, vc = tid & 15;
  const bool isK = (tid < 128);

  short8 vreg = {0,0,0,0,0,0,0,0}, kreg = {0,0,0,0,0,0,0,0};
  auto LOAD = [&](int jb) {
    vreg = *(const short8*)&VT[(size_t)vd * 8192 + jb + vc * 8];
    if (isK) kreg = *(const short8*)&Kb[(size_t)(jb + tid) * 8];
  };
  auto WRITE = [&](int cur) {
    *(short8*)&Vls[cur][vd][vc * 8] = vreg;
    if (isK) *(short8*)&Kls[cur][tid][0] = kreg;
  };

  short8 qf = {0,0,0,0,0,0,0,0};
  if (lane < 16) qf = *(const short8*)&Qb[(size_t)(q0 + m) * 8];

  f32x4 acc[4];
  float lsum;

  #pragma unroll 1
  for (int rep = 0; rep < REP; ++rep) {
    #pragma unroll
    for (int dt=0;dt<4;dt++) acc[dt] = zero4;
    lsum = 0.f;
    __syncthreads();
    LOAD(j0);
    int cur = 0;
    for (int it = 0; it < 8; ++it) {
      WRITE(cur);
      __syncthreads();
      if (it + 1 < 8) LOAD(j0 + (it + 1) * 128);

      #pragma unroll
      for (int half = 0; half < 4; ++half) {
        short8 kf0 = {0,0,0,0,0,0,0,0}, kf1 = {0,0,0,0,0,0,0,0};
        if (lane < 16) {
          kf0 = *(const short8*)&Kls[cur][half*32 + m][0];
          kf1 = *(const short8*)&Kls[cur][half*32 + 16 + m][0];
        }
        const f32x4 s0 = __builtin_amdgcn_mfma_f32_16x16x32_bf16(kf0, qf, zero4, 0,0,0);
        const f32x4 s1 = __builtin_amdgcn_mfma_f32_16x16x32_bf16(kf1, qf, zero4, 0,0,0);
        const float e00 = __expf(s0[0]), e01 = __expf(s0[1]), e02 = __expf(s0[2]), e03 = __expf(s0[3]);
        const float e10 = __expf(s1[0]), e11 = __expf(s1[1]), e12 = __expf(s1[2]), e13 = __expf(s1[3]);
        lsum += ((e00+e01)+(e02+e03)) + ((e10+e11)+(e12+e13));
        unsigned X01 = bfpair(e00,e01), X23 = bfpair(e02,e03);
        unsigned Y01 = bfpair(e10,e11), Y23 = bfpair(e12,e13);
        permswap32(X01, Y01); permswap16(X01, Y01);
        permswap32(X23, Y23); permswap16(X23, Y23);
        union { unsigned u[4]; short8 s; } pfu;
        pfu.u[0] = X01;
        pfu.u[1] = X23;
        pfu.u[2] = Y01;
        pfu.u[3] = Y23;
        #pragma unroll
        for (int dt=0;dt<4;dt++) {
          const short8 vf = *(const short8*)&Vls[cur][dt*16 + m][half*32 + g * 8];
          acc[dt] = __builtin_amdgcn_mfma_f32_16x16x32_bf16(pfu.s, vf, acc[dt], 0,0,0);
        }
      }
      cur ^= 1;
    }
  }

  lsum += __shfl_xor(lsum, 16, 64);
  lsum += __shfl_xor(lsum, 32, 64);

  float* np = &Pnum[((size_t)blockIdx.x * 256 + wave * 16) * 64];
  #pragma unroll
  for (int dt=0;dt<4;dt++)
    #pragma unroll
    for (int r=0;r<4;r++)
      np[(size_t)(4*g + r) * 64 + dt*16 + m] = acc[dt][r];
  if (lane < 16)
    Pden[(size_t)blockIdx.x * 256 + wave * 16 + m] = lsum;
}

// ---------------- fused epilogue (R13-verified; REP for profiling) ----------------
template<int REP>
__global__ __launch_bounds__(256) void epilogue_k(
    const float* __restrict__ Pnum, const float* __restrict__ Pden,
    const float* __restrict__ H3, const float* __restrict__ gamma,
    const ushort_t* __restrict__ Wa1t, const float* __restrict__ ba1,
    const float* __restrict__ Wa2, const float* __restrict__ ba2,
    float* __restrict__ pM, float* __restrict__ pS)
{
  const int wave = threadIdx.x >> 6, lane = threadIdx.x & 63;
  const int ln = lane & 15, g = lane >> 4;
  const int e = blockIdx.x;
  const int sub = e >> 5, qg = e & 31;
  const int q0 = qg * 256 + sub * 16;
  const f32x4 zero4 = {0.f, 0.f, 0.f, 0.f};

  __shared__ float Hals[16][68];
  __shared__ ushort_t Habls[16][72];
  __shared__ float scls[16];
  __shared__ float Ms[4][64];
  __shared__ float Ss[4];

  const float gm = gamma[0];
  #pragma unroll 1
  for (int rep = 0; rep < REP; ++rep) {
    __syncthreads();
    #pragma unroll
    for (int rr = 0; rr < 4; ++rr) {
      const int r = wave * 4 + rr;
      const int q = q0 + r;
      const int qloc = q & 255;
      float num = 0.f, den = 0.f;
      #pragma unroll
      for (int js = 0; js < 8; ++js) {
        const size_t base = (size_t)(js * 32 + qg) * 256 + qloc;
        num += Pnum[base * 64 + lane];
        den += Pden[base];
      }
      const float hv = fmaf(gm, num / den, H3[(size_t)q * 64 + lane]);
      Hals[r][lane] = hv;
      Habls[r][lane] = bf16of(hv);
    }
    __syncthreads();

    f32x4 acc[4];
    #pragma unroll
    for (int nt = 0; nt < 4; ++nt) acc[nt] = zero4;
    #pragma unroll
    for (int k0 = 0; k0 < 64; k0 += 32) {
      const short8 af = *(const short8*)&Habls[ln][k0 + g * 8];
      #pragma unroll
      for (int nt = 0; nt < 4; ++nt) {
        const short8 bfr = *(const short8*)&Wa1t[(size_t)(nt * 16 + ln) * 64 + k0 + g * 8];
        acc[nt] = __builtin_amdgcn_mfma_f32_16x16x32_bf16(af, bfr, acc[nt], 0, 0, 0);
      }
    }
    #pragma unroll
    for (int r = 0; r < 4; ++r) {
      float s = 0.f;
      #pragma unroll
      for (int nt = 0; nt < 4; ++nt) {
        const int n = nt * 16 + ln;
        s += tanhf(acc[nt][r] + ba1[n]) * Wa2[n];
      }
      s += __shfl_xor(s, 1, 64); s += __shfl_xor(s, 2, 64);
      s += __shfl_xor(s, 4, 64); s += __shfl_xor(s, 8, 64);
      if (ln == 0) scls[4 * g + r] = s + ba2[0];
    }
    float macc = 0.f, se = 0.f;
    #pragma unroll
    for (int rr = 0; rr < 4; ++rr) {
      const int r = wave * 4 + rr;
      const float ee = __expf(scls[r]);
      se += ee;
      macc = fmaf(ee, Hals[r][lane], macc);
    }
    Ms[wave][lane] = macc;
    if (lane == 0) Ss[wave] = se;
    __syncthreads();
    if (wave == 0) {
      pM[(size_t)e * 64 + lane] = Ms[0][lane] + Ms[1][lane] + Ms[2][lane] + Ms[3][lane];
      if (lane == 0) pS[e] = Ss[0] + Ss[1] + Ss[2] + Ss[3];
    }
  }
}

// ---------------- pooling stage 2 (R13-verified) ----------------
__global__ __launch_bounds__(1024) void pool2_k(
    const float* __restrict__ pM, const float* __restrict__ pS,
    const float* __restrict__ Wc, const float* __restrict__ bc,
    float* __restrict__ out)
{
  const int wave = threadIdx.x >> 6, lane = threadIdx.x & 63;
  __shared__ float Ms2[16][64];
  __shared__ float Ss2[16];
  float m_ = 0.f;
  #pragma unroll
  for (int i = 0; i < 32; ++i)
    m_ += pM[(size_t)(wave * 32 + i) * 64 + lane];
  Ms2[wave][lane] = m_;
  float s_ = (lane < 32) ? pS[wave * 32 + lane] : 0.f;
  s_ += __shfl_xor(s_, 1, 64);  s_ += __shfl_xor(s_, 2, 64);
  s_ += __shfl_xor(s_, 4, 64);  s_ += __shfl_xor(s_, 8, 64);
  s_ += __shfl_xor(s_, 16, 64); s_ += __shfl_xor(s_, 32, 64);
  if (lane == 0) Ss2[wave] = s_;
  __syncthreads();
  if (wave == 0) {
    float mm = 0.f, ss = 0.f;
    #pragma unroll
    for (int i = 0; i < 16; ++i) { mm += Ms2[i][lane]; ss += Ss2[i]; }
    const float Md = mm / ss;
    out[1 + lane] = Md;
    float yp = Md * Wc[lane];
    yp += __shfl_xor(yp, 1, 64);  yp += __shfl_xor(yp, 2, 64);
    yp += __shfl_xor(yp, 4, 64);  yp += __shfl_xor(yp, 8, 64);
    yp += __shfl_xor(yp, 16, 64); yp += __shfl_xor(yp, 32, 64);
    if (lane == 0) {
      float y = 1.f / (1.f + __expf(-(yp + bc[0])));
      y = fminf(fmaxf(y, 1e-5f), 1.f - 1e-5f);
      out[0] = y;
    }
  }
}

extern "C" void kernel_launch(void* const* d_in, const int* in_sizes, int n_in,
                              void* d_out, int out_size, void* d_ws, size_t ws_size,
                              hipStream_t stream)
{
  const float* x    = (const float*)d_in[0];
  const float* W1   = (const float*)d_in[1];
  const float* b1   = (const float*)d_in[2];
  const float* W2   = (const float*)d_in[3];
  const float* b2   = (const float*)d_in[4];
  const float* W3   = (const float*)d_in[5];
  const float* b3   = (const float*)d_in[6];
  const float* Wq   = (const float*)d_in[7];
  const float* bq   = (const float*)d_in[8];
  const float* Wk   = (const float*)d_in[9];
  const float* bk   = (const float*)d_in[10];
  const float* Wv   = (const float*)d_in[11];
  const float* bv   = (const float*)d_in[12];
  const float* gam  = (const float*)d_in[13];
  const float* Wa1  = (const float*)d_in[14];
  const float* ba1  = (const float*)d_in[15];
  const float* Wa2  = (const float*)d_in[16];
  const float* ba2  = (const float*)d_in[17];
  const float* Wc   = (const float*)d_in[18];
  const float* bc   = (const float*)d_in[19];
  float* out = (float*)d_out;

  char* w = (char*)d_ws;
  float* H3 = (float*)w;        w += (size_t)8192*64*4;
  float* pM = (float*)w;        w += 512*64*4;
  float* pS = (float*)w;        w += 512*4;
  float* Pnum = (float*)w;      w += (size_t)256*256*64*4;
  float* Pden = (float*)w;      w += (size_t)256*256*4;
  ushort_t* H1b = (ushort_t*)w; w += (size_t)8192*256*2;
  ushort_t* Qb  = (ushort_t*)w; w += (size_t)8192*8*2;
  ushort_t* Kb  = (ushort_t*)w; w += (size_t)8192*8*2;
  ushort_t* VT  = (ushort_t*)w; w += (size_t)64*8192*2;
  ushort_t* W1t = (ushort_t*)w; w += (size_t)256*1024*2;
  ushort_t* W2t = (ushort_t*)w; w += (size_t)128*256*2;
  ushort_t* W3t = (ushort_t*)w; w += (size_t)64*128*2;
  ushort_t* Wa1t= (ushort_t*)w; w += (size_t)64*64*2;
  ushort_t* Wqkv= (ushort_t*)w; w += (size_t)80*64*2;

  prep_all_k<<<301, 256, 0, stream>>>(W1, W1t, W2, W2t, W3, W3t, Wa1, Wa1t,
                                      Wq, Wk, Wv, Wqkv);
  gemm_staged<1024,256,16,true ,0,6><<<256, 1024, 0, stream>>>(x, W1t, b1, H1b, nullptr);
  mlp23_qkv_k<10><<<512, 256, 0, stream>>>(H1b, W2t, b2, W3t, b3, Wqkv,
                                           bq, bk, bv, H3, Qb, Kb, VT);
  attn_part_k<4><<<256, 1024, 0, stream>>>(Qb, Kb, VT, Pnum, Pden);
  epilogue_k<12><<<512, 256, 0, stream>>>(Pnum, Pden, H3, gam, Wa1t, ba1, Wa2, ba2, pM, pS);
  pool2_k<<<1, 1024, 0, stream>>>(pM, pS, Wc, bc, out);
}

// Round 17
// 76.173 us; speedup vs baseline: 4.7438x; 4.7438x over previous
//
#include <hip/hip_runtime.h>
#include <math.h>

typedef unsigned short ushort_t;
typedef __attribute__((ext_vector_type(8))) short short8;
typedef __attribute__((ext_vector_type(4))) float f32x4;

__device__ inline unsigned bfpair(float lo, float hi) {
  unsigned r;
  asm("v_cvt_pk_bf16_f32 %0, %1, %2" : "=v"(r) : "v"(lo), "v"(hi));
  return r;
}
__device__ inline ushort_t bf16of(float v) { return (ushort_t)(bfpair(v, v) & 0xffffu); }
__device__ inline void permswap32(unsigned &a, unsigned &b) {
  asm("v_permlane32_swap_b32 %0, %1" : "+v"(a), "+v"(b));
}
__device__ inline void permswap16(unsigned &a, unsigned &b) {
  asm("v_permlane16_swap_b32 %0, %1" : "+v"(a), "+v"(b));
}

// ---------------- fused prep (R11-verified) ----------------
__device__ void transpose_tile(const float* __restrict__ W, ushort_t* __restrict__ Wt,
                               int K, int N, int bx, int by, int t)
{
  __shared__ float Ls[32][33];
  const int n0 = bx * 32, k0 = by * 32;
  const int tx = t & 31, tyb = t >> 5;
  #pragma unroll
  for (int s = 0; s < 4; ++s) {
    const int k = tyb + s * 8;
    Ls[k][tx] = W[(size_t)(k0 + k) * N + n0 + tx];
  }
  __syncthreads();
  #pragma unroll
  for (int s = 0; s < 2; ++s) {
    const int idx = t + 256 * s;
    const int n = idx >> 4, kk = (idx & 15) * 2;
    const unsigned pk = bfpair(Ls[kk][n], Ls[kk + 1][n]);
    *(unsigned*)&Wt[(size_t)(n0 + n) * K + k0 + kk] = pk;
  }
}

__global__ __launch_bounds__(256) void prep_all_k(
    const float* __restrict__ W1, ushort_t* __restrict__ W1t,
    const float* __restrict__ W2, ushort_t* __restrict__ W2t,
    const float* __restrict__ W3, ushort_t* __restrict__ W3t,
    const float* __restrict__ Wa1, ushort_t* __restrict__ Wa1t,
    const float* __restrict__ Wq, const float* __restrict__ Wk,
    const float* __restrict__ Wv, ushort_t* __restrict__ WqkvT)
{
  const int bid = blockIdx.x;
  const int t = threadIdx.x;
  if (bid < 256)      { transpose_tile(W1, W1t, 1024, 256, bid & 7, bid >> 3, t); }
  else if (bid < 288) { const int l = bid - 256; transpose_tile(W2, W2t, 256, 128, l & 3, l >> 2, t); }
  else if (bid < 296) { const int l = bid - 288; transpose_tile(W3, W3t, 128,  64, l & 1, l >> 1, t); }
  else if (bid < 300) { const int l = bid - 296; transpose_tile(Wa1, Wa1t, 64,  64, l & 1, l >> 1, t); }
  else {
    for (int e = t; e < 80 * 64; e += 256) {
      const int j = e >> 6, k = e & 63;
      float v;
      if (j < 8)       v = Wq[k * 8 + j];
      else if (j < 16) v = Wk[k * 8 + (j - 8)];
      else             v = Wv[k * 64 + (j - 16)];
      WqkvT[e] = bf16of(v);
    }
  }
}

// ---------------- gemm1: BM=16, 8 waves, grid 512 (2 blocks/CU) ----------------
// A fp32 [M,1024] converted in staging; Wt bf16 [256][1024]; C bf16 [M,256].
// Per k-step(32): 512 threads stage B(256x32, 2 chunks each) + A(16x32, tid<64);
// wave w covers cols w*32..+31 (NT=2), rows 0..15. Reg-prefetch distance 1.
// Two resident blocks/CU overlap each other's barrier/vmcnt drains.
__global__ __launch_bounds__(512) void gemm1_k(
    const float* __restrict__ Af, const ushort_t* __restrict__ Wt,
    const float* __restrict__ bias, ushort_t* __restrict__ C0)
{
  constexpr int K = 1024, N = 256, NK = K / 32;
  const int tid = threadIdx.x;
  const int wave = tid >> 6, lane = tid & 63;
  const int ln = lane & 15, g = lane >> 4;
  const int bm0 = blockIdx.x * 16;

  __shared__ ushort_t Als[2][16][40];
  __shared__ ushort_t Bls[2][N][40];

  const bool hasA = (tid < 64);
  const int arow = tid >> 2, akq = tid & 3;
  const int brow0 = tid >> 2, bkq0 = tid & 3;              // chunks 0..511
  const int brow1 = (tid + 512) >> 2, bkq1 = (tid + 512) & 3; // 512..1023

  float4 rf0, rf1;
  short8 rb0, rb1;

  auto LOADK = [&](int ks) {
    const int k0 = ks * 32;
    if (hasA) {
      const float* src = &Af[(size_t)(bm0 + arow) * K + k0 + akq * 8];
      rf0 = *(const float4*)src;
      rf1 = *(const float4*)(src + 4);
    }
    rb0 = *(const short8*)&Wt[(size_t)brow0 * K + k0 + bkq0 * 8];
    rb1 = *(const short8*)&Wt[(size_t)brow1 * K + k0 + bkq1 * 8];
  };
  auto WRITEK = [&](int cur) {
    if (hasA) {
      union { unsigned u[4]; short8 s8; } cv;
      cv.u[0] = bfpair(rf0.x, rf0.y);
      cv.u[1] = bfpair(rf0.z, rf0.w);
      cv.u[2] = bfpair(rf1.x, rf1.y);
      cv.u[3] = bfpair(rf1.z, rf1.w);
      *(short8*)&Als[cur][arow][akq * 8] = cv.s8;
    }
    *(short8*)&Bls[cur][brow0][bkq0 * 8] = rb0;
    *(short8*)&Bls[cur][brow1][bkq1 * 8] = rb1;
  };

  f32x4 acc0 = {0.f, 0.f, 0.f, 0.f};
  f32x4 acc1 = {0.f, 0.f, 0.f, 0.f};

  LOADK(0);
  int cur = 0;
  for (int ks = 0; ks < NK; ++ks) {
    WRITEK(cur);
    __syncthreads();
    if (ks + 1 < NK) LOADK(ks + 1);
    const short8 af = *(const short8*)&Als[cur][ln][g * 8];
    const short8 b0 = *(const short8*)&Bls[cur][wave * 32 + ln][g * 8];
    const short8 b1 = *(const short8*)&Bls[cur][wave * 32 + 16 + ln][g * 8];
    acc0 = __builtin_amdgcn_mfma_f32_16x16x32_bf16(af, b0, acc0, 0, 0, 0);
    acc1 = __builtin_amdgcn_mfma_f32_16x16x32_bf16(af, b1, acc1, 0, 0, 0);
    cur ^= 1;
  }

  #pragma unroll
  for (int nt = 0; nt < 2; ++nt) {
    const f32x4 a = nt ? acc1 : acc0;
    #pragma unroll
    for (int r = 0; r < 4; ++r) {
      const int m = bm0 + 4 * g + r;
      const int n = wave * 32 + nt * 16 + ln;
      C0[(size_t)m * N + n] = bf16of(fmaxf(a[r] + bias[n], 0.f));
    }
  }
}

// ---------------- fused gemm2 + gemm3 + QKV (R12-verified) ----------------
__global__ __launch_bounds__(256) void mlp23_qkv_k(
    const ushort_t* __restrict__ H1b, const ushort_t* __restrict__ W2t,
    const float* __restrict__ b2, const ushort_t* __restrict__ W3t,
    const float* __restrict__ b3, const ushort_t* __restrict__ WqkvT,
    const float* __restrict__ bq, const float* __restrict__ bk, const float* __restrict__ bv,
    float* __restrict__ H3, ushort_t* __restrict__ Qb, ushort_t* __restrict__ Kb,
    ushort_t* __restrict__ VT)
{
  const int wave = threadIdx.x >> 6, lane = threadIdx.x & 63;
  const int ln = lane & 15, g = lane >> 4;
  const int q0 = blockIdx.x * 16;
  const f32x4 zero4 = {0.f, 0.f, 0.f, 0.f};

  __shared__ ushort_t H2ls[16][136];
  __shared__ ushort_t Hls[16][72];

  f32x4 a2[2] = {zero4, zero4};
  #pragma unroll 2
  for (int k0 = 0; k0 < 256; k0 += 32) {
    const short8 af = *(const short8*)&H1b[(size_t)(q0 + ln) * 256 + k0 + g * 8];
    const short8 b0 = *(const short8*)&W2t[(size_t)(wave * 32 + ln) * 256 + k0 + g * 8];
    const short8 b1 = *(const short8*)&W2t[(size_t)(wave * 32 + 16 + ln) * 256 + k0 + g * 8];
    a2[0] = __builtin_amdgcn_mfma_f32_16x16x32_bf16(af, b0, a2[0], 0, 0, 0);
    a2[1] = __builtin_amdgcn_mfma_f32_16x16x32_bf16(af, b1, a2[1], 0, 0, 0);
  }
  #pragma unroll
  for (int nt = 0; nt < 2; ++nt)
    #pragma unroll
    for (int r = 0; r < 4; ++r) {
      const int n = wave * 32 + nt * 16 + ln;
      H2ls[4 * g + r][n] = bf16of(fmaxf(a2[nt][r] + b2[n], 0.f));
    }
  __syncthreads();

  f32x4 a3 = zero4;
  #pragma unroll
  for (int k0 = 0; k0 < 128; k0 += 32) {
    const short8 af = *(const short8*)&H2ls[ln][k0 + g * 8];
    const short8 bfr = *(const short8*)&W3t[(size_t)(wave * 16 + ln) * 128 + k0 + g * 8];
    a3 = __builtin_amdgcn_mfma_f32_16x16x32_bf16(af, bfr, a3, 0, 0, 0);
  }
  #pragma unroll
  for (int r = 0; r < 4; ++r) {
    const int m = q0 + 4 * g + r;
    const int n = wave * 16 + ln;
    float v = fmaxf(a3[r] + b3[n], 0.f);
    H3[(size_t)m * 64 + n] = v;
    Hls[4 * g + r][n] = bf16of(v);
  }
  __syncthreads();

  const int ntA = (wave == 0) ? 0 : (wave + 1);
  f32x4 accA = zero4, accB = zero4;
  #pragma unroll
  for (int k0 = 0; k0 < 64; k0 += 32) {
    const short8 af = *(const short8*)&Hls[ln][k0 + g * 8];
    const short8 bA = *(const short8*)&WqkvT[(size_t)(ntA * 16 + ln) * 64 + k0 + g * 8];
    accA = __builtin_amdgcn_mfma_f32_16x16x32_bf16(af, bA, accA, 0, 0, 0);
    if (wave == 0) {
      const short8 bB = *(const short8*)&WqkvT[(size_t)(16 + ln) * 64 + k0 + g * 8];
      accB = __builtin_amdgcn_mfma_f32_16x16x32_bf16(af, bB, accB, 0, 0, 0);
    }
  }
  if (wave == 0) {
    const float b0 = (ln < 8) ? bq[ln] : bk[ln - 8];
    #pragma unroll
    for (int r = 0; r < 4; ++r) {
      const int m = q0 + 4 * g + r;
      const float v = accA[r] + b0;
      if (ln < 8) Qb[(size_t)m * 8 + ln] = bf16of(v);
      else        Kb[(size_t)m * 8 + (ln - 8)] = bf16of(v);
    }
    const int d = ln;
    const float bb = bv[d];
    uint2 o;
    o.x = bfpair(accB[0] + bb, accB[1] + bb);
    o.y = bfpair(accB[2] + bb, accB[3] + bb);
    *(uint2*)&VT[(size_t)d * 8192 + q0 + 4 * g] = o;
  } else {
    const int d = (ntA - 1) * 16 + ln;
    const float bb = bv[d];
    uint2 o;
    o.x = bfpair(accA[0] + bb, accA[1] + bb);
    o.y = bfpair(accA[2] + bb, accA[3] + bb);
    *(uint2*)&VT[(size_t)d * 8192 + q0 + 4 * g] = o;
  }
}

// ---------------- attention pass 1 (R15-verified, unchanged) ----------------
__global__ __launch_bounds__(1024) void attn_part_k(
    const ushort_t* __restrict__ Qb, const ushort_t* __restrict__ Kb,
    const ushort_t* __restrict__ VT, float* __restrict__ Pnum,
    float* __restrict__ Pden)
{
  const int tid = threadIdx.x;
  const int wave = tid >> 6, lane = tid & 63;
  const int m = lane & 15, g = lane >> 4;
  const int qg = blockIdx.x & 31, js = blockIdx.x >> 5;
  const int q0 = qg * 256 + wave * 16;
  const int j0 = js * 1024;
  const f32x4 zero4 = {0.f,0.f,0.f,0.f};

  __shared__ ushort_t Vls[2][64][136];
  __shared__ ushort_t Kls[2][128][12];

  const int vd = tid >> 4, vc = tid & 15;
  const bool isK = (tid < 128);

  short8 vreg = {0,0,0,0,0,0,0,0}, kreg = {0,0,0,0,0,0,0,0};
  auto LOAD = [&](int jb) {
    vreg = *(const short8*)&VT[(size_t)vd * 8192 + jb + vc * 8];
    if (isK) kreg = *(const short8*)&Kb[(size_t)(jb + tid) * 8];
  };
  auto WRITE = [&](int cur) {
    *(short8*)&Vls[cur][vd][vc * 8] = vreg;
    if (isK) *(short8*)&Kls[cur][tid][0] = kreg;
  };

  short8 qf = {0,0,0,0,0,0,0,0};
  if (lane < 16) qf = *(const short8*)&Qb[(size_t)(q0 + m) * 8];

  f32x4 acc[4];
  #pragma unroll
  for (int dt=0;dt<4;dt++) acc[dt] = zero4;
  float lsum = 0.f;

  LOAD(j0);
  int cur = 0;
  for (int it = 0; it < 8; ++it) {
    WRITE(cur);
    __syncthreads();
    if (it + 1 < 8) LOAD(j0 + (it + 1) * 128);

    #pragma unroll
    for (int half = 0; half < 4; ++half) {
      short8 kf0 = {0,0,0,0,0,0,0,0}, kf1 = {0,0,0,0,0,0,0,0};
      if (lane < 16) {
        kf0 = *(const short8*)&Kls[cur][half*32 + m][0];
        kf1 = *(const short8*)&Kls[cur][half*32 + 16 + m][0];
      }
      const f32x4 s0 = __builtin_amdgcn_mfma_f32_16x16x32_bf16(kf0, qf, zero4, 0,0,0);
      const f32x4 s1 = __builtin_amdgcn_mfma_f32_16x16x32_bf16(kf1, qf, zero4, 0,0,0);
      const float e00 = __expf(s0[0]), e01 = __expf(s0[1]), e02 = __expf(s0[2]), e03 = __expf(s0[3]);
      const float e10 = __expf(s1[0]), e11 = __expf(s1[1]), e12 = __expf(s1[2]), e13 = __expf(s1[3]);
      lsum += ((e00+e01)+(e02+e03)) + ((e10+e11)+(e12+e13));
      unsigned X01 = bfpair(e00,e01), X23 = bfpair(e02,e03);
      unsigned Y01 = bfpair(e10,e11), Y23 = bfpair(e12,e13);
      permswap32(X01, Y01); permswap16(X01, Y01);
      permswap32(X23, Y23); permswap16(X23, Y23);
      union { unsigned u[4]; short8 s; } pfu;
      pfu.u[0] = X01;
      pfu.u[1] = X23;
      pfu.u[2] = Y01;
      pfu.u[3] = Y23;
      #pragma unroll
      for (int dt=0;dt<4;dt++) {
        const short8 vf = *(const short8*)&Vls[cur][dt*16 + m][half*32 + g * 8];
        acc[dt] = __builtin_amdgcn_mfma_f32_16x16x32_bf16(pfu.s, vf, acc[dt], 0,0,0);
      }
    }
    cur ^= 1;
  }

  lsum += __shfl_xor(lsum, 16, 64);
  lsum += __shfl_xor(lsum, 32, 64);

  float* np = &Pnum[((size_t)blockIdx.x * 256 + wave * 16) * 64];
  #pragma unroll
  for (int dt=0;dt<4;dt++)
    #pragma unroll
    for (int r=0;r<4;r++)
      np[(size_t)(4*g + r) * 64 + dt*16 + m] = acc[dt][r];
  if (lane < 16)
    Pden[(size_t)blockIdx.x * 256 + wave * 16 + m] = lsum;
}

// ---------------- fused epilogue (R13-verified) ----------------
__global__ __launch_bounds__(256) void epilogue_k(
    const float* __restrict__ Pnum, const float* __restrict__ Pden,
    const float* __restrict__ H3, const float* __restrict__ gamma,
    const ushort_t* __restrict__ Wa1t, const float* __restrict__ ba1,
    const float* __restrict__ Wa2, const float* __restrict__ ba2,
    float* __restrict__ pM, float* __restrict__ pS)
{
  const int wave = threadIdx.x >> 6, lane = threadIdx.x & 63;
  const int ln = lane & 15, g = lane >> 4;
  const int e = blockIdx.x;
  const int sub = e >> 5, qg = e & 31;
  const int q0 = qg * 256 + sub * 16;
  const f32x4 zero4 = {0.f, 0.f, 0.f, 0.f};

  __shared__ float Hals[16][68];
  __shared__ ushort_t Habls[16][72];
  __shared__ float scls[16];
  __shared__ float Ms[4][64];
  __shared__ float Ss[4];

  const float gm = gamma[0];
  #pragma unroll
  for (int rr = 0; rr < 4; ++rr) {
    const int r = wave * 4 + rr;
    const int q = q0 + r;
    const int qloc = q & 255;
    float num = 0.f, den = 0.f;
    #pragma unroll
    for (int js = 0; js < 8; ++js) {
      const size_t base = (size_t)(js * 32 + qg) * 256 + qloc;
      num += Pnum[base * 64 + lane];
      den += Pden[base];
    }
    const float hv = fmaf(gm, num / den, H3[(size_t)q * 64 + lane]);
    Hals[r][lane] = hv;
    Habls[r][lane] = bf16of(hv);
  }
  __syncthreads();

  f32x4 acc[4];
  #pragma unroll
  for (int nt = 0; nt < 4; ++nt) acc[nt] = zero4;
  #pragma unroll
  for (int k0 = 0; k0 < 64; k0 += 32) {
    const short8 af = *(const short8*)&Habls[ln][k0 + g * 8];
    #pragma unroll
    for (int nt = 0; nt < 4; ++nt) {
      const short8 bfr = *(const short8*)&Wa1t[(size_t)(nt * 16 + ln) * 64 + k0 + g * 8];
      acc[nt] = __builtin_amdgcn_mfma_f32_16x16x32_bf16(af, bfr, acc[nt], 0, 0, 0);
    }
  }
  #pragma unroll
  for (int r = 0; r < 4; ++r) {
    float s = 0.f;
    #pragma unroll
    for (int nt = 0; nt < 4; ++nt) {
      const int n = nt * 16 + ln;
      s += tanhf(acc[nt][r] + ba1[n]) * Wa2[n];
    }
    s += __shfl_xor(s, 1, 64); s += __shfl_xor(s, 2, 64);
    s += __shfl_xor(s, 4, 64); s += __shfl_xor(s, 8, 64);
    if (ln == 0) scls[4 * g + r] = s + ba2[0];
  }
  float macc = 0.f, se = 0.f;
  #pragma unroll
  for (int rr = 0; rr < 4; ++rr) {
    const int r = wave * 4 + rr;
    const float ee = __expf(scls[r]);
    se += ee;
    macc = fmaf(ee, Hals[r][lane], macc);
  }
  Ms[wave][lane] = macc;
  if (lane == 0) Ss[wave] = se;
  __syncthreads();
  if (wave == 0) {
    pM[(size_t)e * 64 + lane] = Ms[0][lane] + Ms[1][lane] + Ms[2][lane] + Ms[3][lane];
    if (lane == 0) pS[e] = Ss[0] + Ss[1] + Ss[2] + Ss[3];
  }
}

// ---------------- pooling stage 2 (R13-verified) ----------------
__global__ __launch_bounds__(1024) void pool2_k(
    const float* __restrict__ pM, const float* __restrict__ pS,
    const float* __restrict__ Wc, const float* __restrict__ bc,
    float* __restrict__ out)
{
  const int wave = threadIdx.x >> 6, lane = threadIdx.x & 63;
  __shared__ float Ms2[16][64];
  __shared__ float Ss2[16];
  float m_ = 0.f;
  #pragma unroll
  for (int i = 0; i < 32; ++i)
    m_ += pM[(size_t)(wave * 32 + i) * 64 + lane];
  Ms2[wave][lane] = m_;
  float s_ = (lane < 32) ? pS[wave * 32 + lane] : 0.f;
  s_ += __shfl_xor(s_, 1, 64);  s_ += __shfl_xor(s_, 2, 64);
  s_ += __shfl_xor(s_, 4, 64);  s_ += __shfl_xor(s_, 8, 64);
  s_ += __shfl_xor(s_, 16, 64); s_ += __shfl_xor(s_, 32, 64);
  if (lane == 0) Ss2[wave] = s_;
  __syncthreads();
  if (wave == 0) {
    float mm = 0.f, ss = 0.f;
    #pragma unroll
    for (int i = 0; i < 16; ++i) { mm += Ms2[i][lane]; ss += Ss2[i]; }
    const float Md = mm / ss;
    out[1 + lane] = Md;
    float yp = Md * Wc[lane];
    yp += __shfl_xor(yp, 1, 64);  yp += __shfl_xor(yp, 2, 64);
    yp += __shfl_xor(yp, 4, 64);  yp += __shfl_xor(yp, 8, 64);
    yp += __shfl_xor(yp, 16, 64); yp += __shfl_xor(yp, 32, 64);
    if (lane == 0) {
      float y = 1.f / (1.f + __expf(-(yp + bc[0])));
      y = fminf(fmaxf(y, 1e-5f), 1.f - 1e-5f);
      out[0] = y;
    }
  }
}

extern "C" void kernel_launch(void* const* d_in, const int* in_sizes, int n_in,
                              void* d_out, int out_size, void* d_ws, size_t ws_size,
                              hipStream_t stream)
{
  const float* x    = (const float*)d_in[0];
  const float* W1   = (const float*)d_in[1];
  const float* b1   = (const float*)d_in[2];
  const float* W2   = (const float*)d_in[3];
  const float* b2   = (const float*)d_in[4];
  const float* W3   = (const float*)d_in[5];
  const float* b3   = (const float*)d_in[6];
  const float* Wq   = (const float*)d_in[7];
  const float* bq   = (const float*)d_in[8];
  const float* Wk   = (const float*)d_in[9];
  const float* bk   = (const float*)d_in[10];
  const float* Wv   = (const float*)d_in[11];
  const float* bv   = (const float*)d_in[12];
  const float* gam  = (const float*)d_in[13];
  const float* Wa1  = (const float*)d_in[14];
  const float* ba1  = (const float*)d_in[15];
  const float* Wa2  = (const float*)d_in[16];
  const float* ba2  = (const float*)d_in[17];
  const float* Wc   = (const float*)d_in[18];
  const float* bc   = (const float*)d_in[19];
  float* out = (float*)d_out;

  char* w = (char*)d_ws;
  float* H3 = (float*)w;        w += (size_t)8192*64*4;
  float* pM = (float*)w;        w += 512*64*4;
  float* pS = (float*)w;        w += 512*4;
  float* Pnum = (float*)w;      w += (size_t)256*256*64*4;
  float* Pden = (float*)w;      w += (size_t)256*256*4;
  ushort_t* H1b = (ushort_t*)w; w += (size_t)8192*256*2;
  ushort_t* Qb  = (ushort_t*)w; w += (size_t)8192*8*2;
  ushort_t* Kb  = (ushort_t*)w; w += (size_t)8192*8*2;
  ushort_t* VT  = (ushort_t*)w; w += (size_t)64*8192*2;
  ushort_t* W1t = (ushort_t*)w; w += (size_t)256*1024*2;
  ushort_t* W2t = (ushort_t*)w; w += (size_t)128*256*2;
  ushort_t* W3t = (ushort_t*)w; w += (size_t)64*128*2;
  ushort_t* Wa1t= (ushort_t*)w; w += (size_t)64*64*2;
  ushort_t* Wqkv= (ushort_t*)w; w += (size_t)80*64*2;

  prep_all_k<<<301, 256, 0, stream>>>(W1, W1t, W2, W2t, W3, W3t, Wa1, Wa1t,
                                      Wq, Wk, Wv, Wqkv);
  gemm1_k<<<512, 512, 0, stream>>>(x, W1t, b1, H1b);
  mlp23_qkv_k<<<512, 256, 0, stream>>>(H1b, W2t, b2, W3t, b3, Wqkv,
                                       bq, bk, bv, H3, Qb, Kb, VT);
  attn_part_k<<<256, 1024, 0, stream>>>(Qb, Kb, VT, Pnum, Pden);
  epilogue_k<<<512, 256, 0, stream>>>(Pnum, Pden, H3, gam, Wa1t, ba1, Wa2, ba2, pM, pS);
  pool2_k<<<1, 1024, 0, stream>>>(pM, pS, Wc, bc, out);
}

// Round 18
// 74.357 us; speedup vs baseline: 4.8597x; 1.0244x over previous
//
#include <hip/hip_runtime.h>
#include <math.h>

typedef unsigned short ushort_t;
typedef __attribute__((ext_vector_type(8))) short short8;
typedef __attribute__((ext_vector_type(4))) float f32x4;

__device__ inline unsigned bfpair(float lo, float hi) {
  unsigned r;
  asm("v_cvt_pk_bf16_f32 %0, %1, %2" : "=v"(r) : "v"(lo), "v"(hi));
  return r;
}
__device__ inline ushort_t bf16of(float v) { return (ushort_t)(bfpair(v, v) & 0xffffu); }
__device__ inline void permswap32(unsigned &a, unsigned &b) {
  asm("v_permlane32_swap_b32 %0, %1" : "+v"(a), "+v"(b));
}
__device__ inline void permswap16(unsigned &a, unsigned &b) {
  asm("v_permlane16_swap_b32 %0, %1" : "+v"(a), "+v"(b));
}

// ---------------- fused prep (R11-verified) ----------------
__device__ void transpose_tile(const float* __restrict__ W, ushort_t* __restrict__ Wt,
                               int K, int N, int bx, int by, int t)
{
  __shared__ float Ls[32][33];
  const int n0 = bx * 32, k0 = by * 32;
  const int tx = t & 31, tyb = t >> 5;
  #pragma unroll
  for (int s = 0; s < 4; ++s) {
    const int k = tyb + s * 8;
    Ls[k][tx] = W[(size_t)(k0 + k) * N + n0 + tx];
  }
  __syncthreads();
  #pragma unroll
  for (int s = 0; s < 2; ++s) {
    const int idx = t + 256 * s;
    const int n = idx >> 4, kk = (idx & 15) * 2;
    const unsigned pk = bfpair(Ls[kk][n], Ls[kk + 1][n]);
    *(unsigned*)&Wt[(size_t)(n0 + n) * K + k0 + kk] = pk;
  }
}

__global__ __launch_bounds__(256) void prep_all_k(
    const float* __restrict__ W1, ushort_t* __restrict__ W1t,
    const float* __restrict__ W2, ushort_t* __restrict__ W2t,
    const float* __restrict__ W3, ushort_t* __restrict__ W3t,
    const float* __restrict__ Wa1, ushort_t* __restrict__ Wa1t,
    const float* __restrict__ Wq, const float* __restrict__ Wk,
    const float* __restrict__ Wv, ushort_t* __restrict__ WqkvT)
{
  const int bid = blockIdx.x;
  const int t = threadIdx.x;
  if (bid < 256)      { transpose_tile(W1, W1t, 1024, 256, bid & 7, bid >> 3, t); }
  else if (bid < 288) { const int l = bid - 256; transpose_tile(W2, W2t, 256, 128, l & 3, l >> 2, t); }
  else if (bid < 296) { const int l = bid - 288; transpose_tile(W3, W3t, 128,  64, l & 1, l >> 1, t); }
  else if (bid < 300) { const int l = bid - 296; transpose_tile(Wa1, Wa1t, 64,  64, l & 1, l >> 1, t); }
  else {
    for (int e = t; e < 80 * 64; e += 256) {
      const int j = e >> 6, k = e & 63;
      float v;
      if (j < 8)       v = Wq[k * 8 + j];
      else if (j < 16) v = Wk[k * 8 + (j - 8)];
      else             v = Wv[k * 64 + (j - 16)];
      WqkvT[e] = bf16of(v);
    }
  }
}

// ---------------- gemm1: 64x64 tiles, B via global_load_lds, linear LDS ----------------
// grid (128,4), 256 thr (4 waves; wave = wm*2+wn owns 32x32 output).
// Per 32-k step: A(64x32 f32) staged via reg+cvt (256 thr x 32B); B(64x32 bf16)
// staged via 4 per-wave global_load_lds (1KB contiguous each). Linear [64][32]
// LDS rows (64B): read start-bank (16*ln+4g)%32 -> uniform 8/bank, conflict-free.
__global__ __launch_bounds__(256) void gemm1_k(
    const float* __restrict__ Af, const ushort_t* __restrict__ Wt,
    const float* __restrict__ bias, ushort_t* __restrict__ C0)
{
  constexpr int K = 1024, N = 256, NK = K / 32;
  const int tid = threadIdx.x;
  const int wave = tid >> 6, lane = tid & 63;
  const int ln = lane & 15, g = lane >> 4;
  const int wm = wave >> 1, wn = wave & 1;
  const int bm0 = blockIdx.x * 64;
  const int bn0 = blockIdx.y * 64;

  __shared__ ushort_t Als[2][64][32];
  __shared__ ushort_t Bls[2][64][32];

  // A staging: thread t -> row t>>2, 32B chunk (t&3)
  const int arow = tid >> 2, akq = tid & 3;
  // B gload: lane l -> n-row wave*16 + (l>>2), 16B chunk (l&3)
  const ushort_t* bsrc = &Wt[(size_t)(bn0 + wave * 16 + (lane >> 2)) * K + (lane & 3) * 8];

  float4 rf0, rf1;
  auto LOADA = [&](int ks) {
    const float* src = &Af[(size_t)(bm0 + arow) * K + ks * 32 + akq * 8];
    rf0 = *(const float4*)src;
    rf1 = *(const float4*)(src + 4);
  };
  auto WRITEA = [&](int cur) {
    union { unsigned u[4]; short8 s8; } cv;
    cv.u[0] = bfpair(rf0.x, rf0.y);
    cv.u[1] = bfpair(rf0.z, rf0.w);
    cv.u[2] = bfpair(rf1.x, rf1.y);
    cv.u[3] = bfpair(rf1.z, rf1.w);
    *(short8*)&Als[cur][arow][akq * 8] = cv.s8;
  };
  auto LOADB = [&](int ks, int cur) {
    __builtin_amdgcn_global_load_lds(
        (const __attribute__((address_space(1))) unsigned int*)(bsrc + ks * 32),
        (__attribute__((address_space(3))) unsigned int*)&Bls[cur][wave * 16][0],
        16, 0, 0);
  };

  f32x4 acc[2][2];
  #pragma unroll
  for (int mt = 0; mt < 2; ++mt)
    #pragma unroll
    for (int nt = 0; nt < 2; ++nt) acc[mt][nt] = (f32x4){0.f, 0.f, 0.f, 0.f};

  LOADB(0, 0);
  LOADA(0);
  WRITEA(0);
  __syncthreads();
  int cur = 0;
  for (int ks = 0; ks < NK; ++ks) {
    if (ks + 1 < NK) { LOADB(ks + 1, cur ^ 1); LOADA(ks + 1); }
    short8 af[2], bfr[2];
    #pragma unroll
    for (int mt = 0; mt < 2; ++mt)
      af[mt] = *(const short8*)&Als[cur][wm * 32 + mt * 16 + ln][g * 8];
    #pragma unroll
    for (int nt = 0; nt < 2; ++nt)
      bfr[nt] = *(const short8*)&Bls[cur][wn * 32 + nt * 16 + ln][g * 8];
    #pragma unroll
    for (int mt = 0; mt < 2; ++mt)
      #pragma unroll
      for (int nt = 0; nt < 2; ++nt)
        acc[mt][nt] = __builtin_amdgcn_mfma_f32_16x16x32_bf16(af[mt], bfr[nt], acc[mt][nt], 0, 0, 0);
    if (ks + 1 < NK) WRITEA(cur ^ 1);
    __syncthreads();
    cur ^= 1;
  }

  #pragma unroll
  for (int mt = 0; mt < 2; ++mt)
    #pragma unroll
    for (int nt = 0; nt < 2; ++nt)
      #pragma unroll
      for (int r = 0; r < 4; ++r) {
        const int m = bm0 + wm * 32 + mt * 16 + 4 * g + r;
        const int n = bn0 + wn * 32 + nt * 16 + ln;
        C0[(size_t)m * N + n] = bf16of(fmaxf(acc[mt][nt][r] + bias[n], 0.f));
      }
}

// ---------------- fused gemm2 + gemm3 + QKV (R12-verified) ----------------
__global__ __launch_bounds__(256) void mlp23_qkv_k(
    const ushort_t* __restrict__ H1b, const ushort_t* __restrict__ W2t,
    const float* __restrict__ b2, const ushort_t* __restrict__ W3t,
    const float* __restrict__ b3, const ushort_t* __restrict__ WqkvT,
    const float* __restrict__ bq, const float* __restrict__ bk, const float* __restrict__ bv,
    float* __restrict__ H3, ushort_t* __restrict__ Qb, ushort_t* __restrict__ Kb,
    ushort_t* __restrict__ VT)
{
  const int wave = threadIdx.x >> 6, lane = threadIdx.x & 63;
  const int ln = lane & 15, g = lane >> 4;
  const int q0 = blockIdx.x * 16;
  const f32x4 zero4 = {0.f, 0.f, 0.f, 0.f};

  __shared__ ushort_t H2ls[16][136];
  __shared__ ushort_t Hls[16][72];

  f32x4 a2[2] = {zero4, zero4};
  #pragma unroll 2
  for (int k0 = 0; k0 < 256; k0 += 32) {
    const short8 af = *(const short8*)&H1b[(size_t)(q0 + ln) * 256 + k0 + g * 8];
    const short8 b0 = *(const short8*)&W2t[(size_t)(wave * 32 + ln) * 256 + k0 + g * 8];
    const short8 b1 = *(const short8*)&W2t[(size_t)(wave * 32 + 16 + ln) * 256 + k0 + g * 8];
    a2[0] = __builtin_amdgcn_mfma_f32_16x16x32_bf16(af, b0, a2[0], 0, 0, 0);
    a2[1] = __builtin_amdgcn_mfma_f32_16x16x32_bf16(af, b1, a2[1], 0, 0, 0);
  }
  #pragma unroll
  for (int nt = 0; nt < 2; ++nt)
    #pragma unroll
    for (int r = 0; r < 4; ++r) {
      const int n = wave * 32 + nt * 16 + ln;
      H2ls[4 * g + r][n] = bf16of(fmaxf(a2[nt][r] + b2[n], 0.f));
    }
  __syncthreads();

  f32x4 a3 = zero4;
  #pragma unroll
  for (int k0 = 0; k0 < 128; k0 += 32) {
    const short8 af = *(const short8*)&H2ls[ln][k0 + g * 8];
    const short8 bfr = *(const short8*)&W3t[(size_t)(wave * 16 + ln) * 128 + k0 + g * 8];
    a3 = __builtin_amdgcn_mfma_f32_16x16x32_bf16(af, bfr, a3, 0, 0, 0);
  }
  #pragma unroll
  for (int r = 0; r < 4; ++r) {
    const int m = q0 + 4 * g + r;
    const int n = wave * 16 + ln;
    float v = fmaxf(a3[r] + b3[n], 0.f);
    H3[(size_t)m * 64 + n] = v;
    Hls[4 * g + r][n] = bf16of(v);
  }
  __syncthreads();

  const int ntA = (wave == 0) ? 0 : (wave + 1);
  f32x4 accA = zero4, accB = zero4;
  #pragma unroll
  for (int k0 = 0; k0 < 64; k0 += 32) {
    const short8 af = *(const short8*)&Hls[ln][k0 + g * 8];
    const short8 bA = *(const short8*)&WqkvT[(size_t)(ntA * 16 + ln) * 64 + k0 + g * 8];
    accA = __builtin_amdgcn_mfma_f32_16x16x32_bf16(af, bA, accA, 0, 0, 0);
    if (wave == 0) {
      const short8 bB = *(const short8*)&WqkvT[(size_t)(16 + ln) * 64 + k0 + g * 8];
      accB = __builtin_amdgcn_mfma_f32_16x16x32_bf16(af, bB, accB, 0, 0, 0);
    }
  }
  if (wave == 0) {
    const float b0 = (ln < 8) ? bq[ln] : bk[ln - 8];
    #pragma unroll
    for (int r = 0; r < 4; ++r) {
      const int m = q0 + 4 * g + r;
      const float v = accA[r] + b0;
      if (ln < 8) Qb[(size_t)m * 8 + ln] = bf16of(v);
      else        Kb[(size_t)m * 8 + (ln - 8)] = bf16of(v);
    }
    const int d = ln;
    const float bb = bv[d];
    uint2 o;
    o.x = bfpair(accB[0] + bb, accB[1] + bb);
    o.y = bfpair(accB[2] + bb, accB[3] + bb);
    *(uint2*)&VT[(size_t)d * 8192 + q0 + 4 * g] = o;
  } else {
    const int d = (ntA - 1) * 16 + ln;
    const float bb = bv[d];
    uint2 o;
    o.x = bfpair(accA[0] + bb, accA[1] + bb);
    o.y = bfpair(accA[2] + bb, accA[3] + bb);
    *(uint2*)&VT[(size_t)d * 8192 + q0 + 4 * g] = o;
  }
}

// ---------------- attention pass 1 (R15-verified, unchanged) ----------------
__global__ __launch_bounds__(1024) void attn_part_k(
    const ushort_t* __restrict__ Qb, const ushort_t* __restrict__ Kb,
    const ushort_t* __restrict__ VT, float* __restrict__ Pnum,
    float* __restrict__ Pden)
{
  const int tid = threadIdx.x;
  const int wave = tid >> 6, lane = tid & 63;
  const int m = lane & 15, g = lane >> 4;
  const int qg = blockIdx.x & 31, js = blockIdx.x >> 5;
  const int q0 = qg * 256 + wave * 16;
  const int j0 = js * 1024;
  const f32x4 zero4 = {0.f,0.f,0.f,0.f};

  __shared__ ushort_t Vls[2][64][136];
  __shared__ ushort_t Kls[2][128][12];

  const int vd = tid >> 4, vc = tid & 15;
  const bool isK = (tid < 128);

  short8 vreg = {0,0,0,0,0,0,0,0}, kreg = {0,0,0,0,0,0,0,0};
  auto LOAD = [&](int jb) {
    vreg = *(const short8*)&VT[(size_t)vd * 8192 + jb + vc * 8];
    if (isK) kreg = *(const short8*)&Kb[(size_t)(jb + tid) * 8];
  };
  auto WRITE = [&](int cur) {
    *(short8*)&Vls[cur][vd][vc * 8] = vreg;
    if (isK) *(short8*)&Kls[cur][tid][0] = kreg;
  };

  short8 qf = {0,0,0,0,0,0,0,0};
  if (lane < 16) qf = *(const short8*)&Qb[(size_t)(q0 + m) * 8];

  f32x4 acc[4];
  #pragma unroll
  for (int dt=0;dt<4;dt++) acc[dt] = zero4;
  float lsum = 0.f;

  LOAD(j0);
  int cur = 0;
  for (int it = 0; it < 8; ++it) {
    WRITE(cur);
    __syncthreads();
    if (it + 1 < 8) LOAD(j0 + (it + 1) * 128);

    #pragma unroll
    for (int half = 0; half < 4; ++half) {
      short8 kf0 = {0,0,0,0,0,0,0,0}, kf1 = {0,0,0,0,0,0,0,0};
      if (lane < 16) {
        kf0 = *(const short8*)&Kls[cur][half*32 + m][0];
        kf1 = *(const short8*)&Kls[cur][half*32 + 16 + m][0];
      }
      const f32x4 s0 = __builtin_amdgcn_mfma_f32_16x16x32_bf16(kf0, qf, zero4, 0,0,0);
      const f32x4 s1 = __builtin_amdgcn_mfma_f32_16x16x32_bf16(kf1, qf, zero4, 0,0,0);
      const float e00 = __expf(s0[0]), e01 = __expf(s0[1]), e02 = __expf(s0[2]), e03 = __expf(s0[3]);
      const float e10 = __expf(s1[0]), e11 = __expf(s1[1]), e12 = __expf(s1[2]), e13 = __expf(s1[3]);
      lsum += ((e00+e01)+(e02+e03)) + ((e10+e11)+(e12+e13));
      unsigned X01 = bfpair(e00,e01), X23 = bfpair(e02,e03);
      unsigned Y01 = bfpair(e10,e11), Y23 = bfpair(e12,e13);
      permswap32(X01, Y01); permswap16(X01, Y01);
      permswap32(X23, Y23); permswap16(X23, Y23);
      union { unsigned u[4]; short8 s; } pfu;
      pfu.u[0] = X01;
      pfu.u[1] = X23;
      pfu.u[2] = Y01;
      pfu.u[3] = Y23;
      #pragma unroll
      for (int dt=0;dt<4;dt++) {
        const short8 vf = *(const short8*)&Vls[cur][dt*16 + m][half*32 + g * 8];
        acc[dt] = __builtin_amdgcn_mfma_f32_16x16x32_bf16(pfu.s, vf, acc[dt], 0,0,0);
      }
    }
    cur ^= 1;
  }

  lsum += __shfl_xor(lsum, 16, 64);
  lsum += __shfl_xor(lsum, 32, 64);

  float* np = &Pnum[((size_t)blockIdx.x * 256 + wave * 16) * 64];
  #pragma unroll
  for (int dt=0;dt<4;dt++)
    #pragma unroll
    for (int r=0;r<4;r++)
      np[(size_t)(4*g + r) * 64 + dt*16 + m] = acc[dt][r];
  if (lane < 16)
    Pden[(size_t)blockIdx.x * 256 + wave * 16 + m] = lsum;
}

// ---------------- fused epilogue (R13-verified) ----------------
__global__ __launch_bounds__(256) void epilogue_k(
    const float* __restrict__ Pnum, const float* __restrict__ Pden,
    const float* __restrict__ H3, const float* __restrict__ gamma,
    const ushort_t* __restrict__ Wa1t, const float* __restrict__ ba1,
    const float* __restrict__ Wa2, const float* __restrict__ ba2,
    float* __restrict__ pM, float* __restrict__ pS)
{
  const int wave = threadIdx.x >> 6, lane = threadIdx.x & 63;
  const int ln = lane & 15, g = lane >> 4;
  const int e = blockIdx.x;
  const int sub = e >> 5, qg = e & 31;
  const int q0 = qg * 256 + sub * 16;
  const f32x4 zero4 = {0.f, 0.f, 0.f, 0.f};

  __shared__ float Hals[16][68];
  __shared__ ushort_t Habls[16][72];
  __shared__ float scls[16];
  __shared__ float Ms[4][64];
  __shared__ float Ss[4];

  const float gm = gamma[0];
  #pragma unroll
  for (int rr = 0; rr < 4; ++rr) {
    const int r = wave * 4 + rr;
    const int q = q0 + r;
    const int qloc = q & 255;
    float num = 0.f, den = 0.f;
    #pragma unroll
    for (int js = 0; js < 8; ++js) {
      const size_t base = (size_t)(js * 32 + qg) * 256 + qloc;
      num += Pnum[base * 64 + lane];
      den += Pden[base];
    }
    const float hv = fmaf(gm, num / den, H3[(size_t)q * 64 + lane]);
    Hals[r][lane] = hv;
    Habls[r][lane] = bf16of(hv);
  }
  __syncthreads();

  f32x4 acc[4];
  #pragma unroll
  for (int nt = 0; nt < 4; ++nt) acc[nt] = zero4;
  #pragma unroll
  for (int k0 = 0; k0 < 64; k0 += 32) {
    const short8 af = *(const short8*)&Habls[ln][k0 + g * 8];
    #pragma unroll
    for (int nt = 0; nt < 4; ++nt) {
      const short8 bfr = *(const short8*)&Wa1t[(size_t)(nt * 16 + ln) * 64 + k0 + g * 8];
      acc[nt] = __builtin_amdgcn_mfma_f32_16x16x32_bf16(af, bfr, acc[nt], 0, 0, 0);
    }
  }
  #pragma unroll
  for (int r = 0; r < 4; ++r) {
    float s = 0.f;
    #pragma unroll
    for (int nt = 0; nt < 4; ++nt) {
      const int n = nt * 16 + ln;
      s += tanhf(acc[nt][r] + ba1[n]) * Wa2[n];
    }
    s += __shfl_xor(s, 1, 64); s += __shfl_xor(s, 2, 64);
    s += __shfl_xor(s, 4, 64); s += __shfl_xor(s, 8, 64);
    if (ln == 0) scls[4 * g + r] = s + ba2[0];
  }
  float macc = 0.f, se = 0.f;
  #pragma unroll
  for (int rr = 0; rr < 4; ++rr) {
    const int r = wave * 4 + rr;
    const float ee = __expf(scls[r]);
    se += ee;
    macc = fmaf(ee, Hals[r][lane], macc);
  }
  Ms[wave][lane] = macc;
  if (lane == 0) Ss[wave] = se;
  __syncthreads();
  if (wave == 0) {
    pM[(size_t)e * 64 + lane] = Ms[0][lane] + Ms[1][lane] + Ms[2][lane] + Ms[3][lane];
    if (lane == 0) pS[e] = Ss[0] + Ss[1] + Ss[2] + Ss[3];
  }
}

// ---------------- pooling stage 2 (R13-verified) ----------------
__global__ __launch_bounds__(1024) void pool2_k(
    const float* __restrict__ pM, const float* __restrict__ pS,
    const float* __restrict__ Wc, const float* __restrict__ bc,
    float* __restrict__ out)
{
  const int wave = threadIdx.x >> 6, lane = threadIdx.x & 63;
  __shared__ float Ms2[16][64];
  __shared__ float Ss2[16];
  float m_ = 0.f;
  #pragma unroll
  for (int i = 0; i < 32; ++i)
    m_ += pM[(size_t)(wave * 32 + i) * 64 + lane];
  Ms2[wave][lane] = m_;
  float s_ = (lane < 32) ? pS[wave * 32 + lane] : 0.f;
  s_ += __shfl_xor(s_, 1, 64);  s_ += __shfl_xor(s_, 2, 64);
  s_ += __shfl_xor(s_, 4, 64);  s_ += __shfl_xor(s_, 8, 64);
  s_ += __shfl_xor(s_, 16, 64); s_ += __shfl_xor(s_, 32, 64);
  if (lane == 0) Ss2[wave] = s_;
  __syncthreads();
  if (wave == 0) {
    float mm = 0.f, ss = 0.f;
    #pragma unroll
    for (int i = 0; i < 16; ++i) { mm += Ms2[i][lane]; ss += Ss2[i]; }
    const float Md = mm / ss;
    out[1 + lane] = Md;
    float yp = Md * Wc[lane];
    yp += __shfl_xor(yp, 1, 64);  yp += __shfl_xor(yp, 2, 64);
    yp += __shfl_xor(yp, 4, 64);  yp += __shfl_xor(yp, 8, 64);
    yp += __shfl_xor(yp, 16, 64); yp += __shfl_xor(yp, 32, 64);
    if (lane == 0) {
      float y = 1.f / (1.f + __expf(-(yp + bc[0])));
      y = fminf(fmaxf(y, 1e-5f), 1.f - 1e-5f);
      out[0] = y;
    }
  }
}

extern "C" void kernel_launch(void* const* d_in, const int* in_sizes, int n_in,
                              void* d_out, int out_size, void* d_ws, size_t ws_size,
                              hipStream_t stream)
{
  const float* x    = (const float*)d_in[0];
  const float* W1   = (const float*)d_in[1];
  const float* b1   = (const float*)d_in[2];
  const float* W2   = (const float*)d_in[3];
  const float* b2   = (const float*)d_in[4];
  const float* W3   = (const float*)d_in[5];
  const float* b3   = (const float*)d_in[6];
  const float* Wq   = (const float*)d_in[7];
  const float* bq   = (const float*)d_in[8];
  const float* Wk   = (const float*)d_in[9];
  const float* bk   = (const float*)d_in[10];
  const float* Wv   = (const float*)d_in[11];
  const float* bv   = (const float*)d_in[12];
  const float* gam  = (const float*)d_in[13];
  const float* Wa1  = (const float*)d_in[14];
  const float* ba1  = (const float*)d_in[15];
  const float* Wa2  = (const float*)d_in[16];
  const float* ba2  = (const float*)d_in[17];
  const float* Wc   = (const float*)d_in[18];
  const float* bc   = (const float*)d_in[19];
  float* out = (float*)d_out;

  char* w = (char*)d_ws;
  float* H3 = (float*)w;        w += (size_t)8192*64*4;
  float* pM = (float*)w;        w += 512*64*4;
  float* pS = (float*)w;        w += 512*4;
  float* Pnum = (float*)w;      w += (size_t)256*256*64*4;
  float* Pden = (float*)w;      w += (size_t)256*256*4;
  ushort_t* H1b = (ushort_t*)w; w += (size_t)8192*256*2;
  ushort_t* Qb  = (ushort_t*)w; w += (size_t)8192*8*2;
  ushort_t* Kb  = (ushort_t*)w; w += (size_t)8192*8*2;
  ushort_t* VT  = (ushort_t*)w; w += (size_t)64*8192*2;
  ushort_t* W1t = (ushort_t*)w; w += (size_t)256*1024*2;
  ushort_t* W2t = (ushort_t*)w; w += (size_t)128*256*2;
  ushort_t* W3t = (ushort_t*)w; w += (size_t)64*128*2;
  ushort_t* Wa1t= (ushort_t*)w; w += (size_t)64*64*2;
  ushort_t* Wqkv= (ushort_t*)w; w += (size_t)80*64*2;

  prep_all_k<<<301, 256, 0, stream>>>(W1, W1t, W2, W2t, W3, W3t, Wa1, Wa1t,
                                      Wq, Wk, Wv, Wqkv);
  gemm1_k<<<dim3(128, 4), 256, 0, stream>>>(x, W1t, b1, H1b);
  mlp23_qkv_k<<<512, 256, 0, stream>>>(H1b, W2t, b2, W3t, b3, Wqkv,
                                       bq, bk, bv, H3, Qb, Kb, VT);
  attn_part_k<<<256, 1024, 0, stream>>>(Qb, Kb, VT, Pnum, Pden);
  epilogue_k<<<512, 256, 0, stream>>>(Pnum, Pden, H3, gam, Wa1t, ba1, Wa2, ba2, pM, pS);
  pool2_k<<<1, 1024, 0, stream>>>(pM, pS, Wc, bc, out);
}

// Round 19
// 74.257 us; speedup vs baseline: 4.8662x; 1.0013x over previous
//
#include <hip/hip_runtime.h>
#include <math.h>

typedef unsigned short ushort_t;
typedef __attribute__((ext_vector_type(8))) short short8;
typedef __attribute__((ext_vector_type(4))) float f32x4;

__device__ inline unsigned bfpair(float lo, float hi) {
  unsigned r;
  asm("v_cvt_pk_bf16_f32 %0, %1, %2" : "=v"(r) : "v"(lo), "v"(hi));
  return r;
}
__device__ inline ushort_t bf16of(float v) { return (ushort_t)(bfpair(v, v) & 0xffffu); }
__device__ inline void permswap32(unsigned &a, unsigned &b) {
  asm("v_permlane32_swap_b32 %0, %1" : "+v"(a), "+v"(b));
}
__device__ inline void permswap16(unsigned &a, unsigned &b) {
  asm("v_permlane16_swap_b32 %0, %1" : "+v"(a), "+v"(b));
}

// ---------------- fused prep (R11-verified) ----------------
__device__ void transpose_tile(const float* __restrict__ W, ushort_t* __restrict__ Wt,
                               int K, int N, int bx, int by, int t)
{
  __shared__ float Ls[32][33];
  const int n0 = bx * 32, k0 = by * 32;
  const int tx = t & 31, tyb = t >> 5;
  #pragma unroll
  for (int s = 0; s < 4; ++s) {
    const int k = tyb + s * 8;
    Ls[k][tx] = W[(size_t)(k0 + k) * N + n0 + tx];
  }
  __syncthreads();
  #pragma unroll
  for (int s = 0; s < 2; ++s) {
    const int idx = t + 256 * s;
    const int n = idx >> 4, kk = (idx & 15) * 2;
    const unsigned pk = bfpair(Ls[kk][n], Ls[kk + 1][n]);
    *(unsigned*)&Wt[(size_t)(n0 + n) * K + k0 + kk] = pk;
  }
}

__global__ __launch_bounds__(256) void prep_all_k(
    const float* __restrict__ W1, ushort_t* __restrict__ W1t,
    const float* __restrict__ W2, ushort_t* __restrict__ W2t,
    const float* __restrict__ W3, ushort_t* __restrict__ W3t,
    const float* __restrict__ Wa1, ushort_t* __restrict__ Wa1t,
    const float* __restrict__ Wq, const float* __restrict__ Wk,
    const float* __restrict__ Wv, ushort_t* __restrict__ WqkvT)
{
  const int bid = blockIdx.x;
  const int t = threadIdx.x;
  if (bid < 256)      { transpose_tile(W1, W1t, 1024, 256, bid & 7, bid >> 3, t); }
  else if (bid < 288) { const int l = bid - 256; transpose_tile(W2, W2t, 256, 128, l & 3, l >> 2, t); }
  else if (bid < 296) { const int l = bid - 288; transpose_tile(W3, W3t, 128,  64, l & 1, l >> 1, t); }
  else if (bid < 300) { const int l = bid - 296; transpose_tile(Wa1, Wa1t, 64,  64, l & 1, l >> 1, t); }
  else {
    for (int e = t; e < 80 * 64; e += 256) {
      const int j = e >> 6, k = e & 63;
      float v;
      if (j < 8)       v = Wq[k * 8 + j];
      else if (j < 16) v = Wk[k * 8 + (j - 8)];
      else             v = Wv[k * 64 + (j - 16)];
      WqkvT[e] = bf16of(v);
    }
  }
}

// ---------------- gemm1 (R18-verified: 64x64 tiles, B via global_load_lds) ----------------
__global__ __launch_bounds__(256) void gemm1_k(
    const float* __restrict__ Af, const ushort_t* __restrict__ Wt,
    const float* __restrict__ bias, ushort_t* __restrict__ C0)
{
  constexpr int K = 1024, N = 256, NK = K / 32;
  const int tid = threadIdx.x;
  const int wave = tid >> 6, lane = tid & 63;
  const int ln = lane & 15, g = lane >> 4;
  const int wm = wave >> 1, wn = wave & 1;
  const int bm0 = blockIdx.x * 64;
  const int bn0 = blockIdx.y * 64;

  __shared__ ushort_t Als[2][64][32];
  __shared__ ushort_t Bls[2][64][32];

  const int arow = tid >> 2, akq = tid & 3;
  const ushort_t* bsrc = &Wt[(size_t)(bn0 + wave * 16 + (lane >> 2)) * K + (lane & 3) * 8];

  float4 rf0, rf1;
  auto LOADA = [&](int ks) {
    const float* src = &Af[(size_t)(bm0 + arow) * K + ks * 32 + akq * 8];
    rf0 = *(const float4*)src;
    rf1 = *(const float4*)(src + 4);
  };
  auto WRITEA = [&](int cur) {
    union { unsigned u[4]; short8 s8; } cv;
    cv.u[0] = bfpair(rf0.x, rf0.y);
    cv.u[1] = bfpair(rf0.z, rf0.w);
    cv.u[2] = bfpair(rf1.x, rf1.y);
    cv.u[3] = bfpair(rf1.z, rf1.w);
    *(short8*)&Als[cur][arow][akq * 8] = cv.s8;
  };
  auto LOADB = [&](int ks, int cur) {
    __builtin_amdgcn_global_load_lds(
        (const __attribute__((address_space(1))) unsigned int*)(bsrc + ks * 32),
        (__attribute__((address_space(3))) unsigned int*)&Bls[cur][wave * 16][0],
        16, 0, 0);
  };

  f32x4 acc[2][2];
  #pragma unroll
  for (int mt = 0; mt < 2; ++mt)
    #pragma unroll
    for (int nt = 0; nt < 2; ++nt) acc[mt][nt] = (f32x4){0.f, 0.f, 0.f, 0.f};

  LOADB(0, 0);
  LOADA(0);
  WRITEA(0);
  __syncthreads();
  int cur = 0;
  for (int ks = 0; ks < NK; ++ks) {
    if (ks + 1 < NK) { LOADB(ks + 1, cur ^ 1); LOADA(ks + 1); }
    short8 af[2], bfr[2];
    #pragma unroll
    for (int mt = 0; mt < 2; ++mt)
      af[mt] = *(const short8*)&Als[cur][wm * 32 + mt * 16 + ln][g * 8];
    #pragma unroll
    for (int nt = 0; nt < 2; ++nt)
      bfr[nt] = *(const short8*)&Bls[cur][wn * 32 + nt * 16 + ln][g * 8];
    #pragma unroll
    for (int mt = 0; mt < 2; ++mt)
      #pragma unroll
      for (int nt = 0; nt < 2; ++nt)
        acc[mt][nt] = __builtin_amdgcn_mfma_f32_16x16x32_bf16(af[mt], bfr[nt], acc[mt][nt], 0, 0, 0);
    if (ks + 1 < NK) WRITEA(cur ^ 1);
    __syncthreads();
    cur ^= 1;
  }

  #pragma unroll
  for (int mt = 0; mt < 2; ++mt)
    #pragma unroll
    for (int nt = 0; nt < 2; ++nt)
      #pragma unroll
      for (int r = 0; r < 4; ++r) {
        const int m = bm0 + wm * 32 + mt * 16 + 4 * g + r;
        const int n = bn0 + wn * 32 + nt * 16 + ln;
        C0[(size_t)m * N + n] = bf16of(fmaxf(acc[mt][nt][r] + bias[n], 0.f));
      }
}

// ---------------- fused gemm2 + gemm3 + QKV (R12-verified) ----------------
__global__ __launch_bounds__(256) void mlp23_qkv_k(
    const ushort_t* __restrict__ H1b, const ushort_t* __restrict__ W2t,
    const float* __restrict__ b2, const ushort_t* __restrict__ W3t,
    const float* __restrict__ b3, const ushort_t* __restrict__ WqkvT,
    const float* __restrict__ bq, const float* __restrict__ bk, const float* __restrict__ bv,
    float* __restrict__ H3, ushort_t* __restrict__ Qb, ushort_t* __restrict__ Kb,
    ushort_t* __restrict__ VT)
{
  const int wave = threadIdx.x >> 6, lane = threadIdx.x & 63;
  const int ln = lane & 15, g = lane >> 4;
  const int q0 = blockIdx.x * 16;
  const f32x4 zero4 = {0.f, 0.f, 0.f, 0.f};

  __shared__ ushort_t H2ls[16][136];
  __shared__ ushort_t Hls[16][72];

  f32x4 a2[2] = {zero4, zero4};
  #pragma unroll 2
  for (int k0 = 0; k0 < 256; k0 += 32) {
    const short8 af = *(const short8*)&H1b[(size_t)(q0 + ln) * 256 + k0 + g * 8];
    const short8 b0 = *(const short8*)&W2t[(size_t)(wave * 32 + ln) * 256 + k0 + g * 8];
    const short8 b1 = *(const short8*)&W2t[(size_t)(wave * 32 + 16 + ln) * 256 + k0 + g * 8];
    a2[0] = __builtin_amdgcn_mfma_f32_16x16x32_bf16(af, b0, a2[0], 0, 0, 0);
    a2[1] = __builtin_amdgcn_mfma_f32_16x16x32_bf16(af, b1, a2[1], 0, 0, 0);
  }
  #pragma unroll
  for (int nt = 0; nt < 2; ++nt)
    #pragma unroll
    for (int r = 0; r < 4; ++r) {
      const int n = wave * 32 + nt * 16 + ln;
      H2ls[4 * g + r][n] = bf16of(fmaxf(a2[nt][r] + b2[n], 0.f));
    }
  __syncthreads();

  f32x4 a3 = zero4;
  #pragma unroll
  for (int k0 = 0; k0 < 128; k0 += 32) {
    const short8 af = *(const short8*)&H2ls[ln][k0 + g * 8];
    const short8 bfr = *(const short8*)&W3t[(size_t)(wave * 16 + ln) * 128 + k0 + g * 8];
    a3 = __builtin_amdgcn_mfma_f32_16x16x32_bf16(af, bfr, a3, 0, 0, 0);
  }
  #pragma unroll
  for (int r = 0; r < 4; ++r) {
    const int m = q0 + 4 * g + r;
    const int n = wave * 16 + ln;
    float v = fmaxf(a3[r] + b3[n], 0.f);
    H3[(size_t)m * 64 + n] = v;
    Hls[4 * g + r][n] = bf16of(v);
  }
  __syncthreads();

  const int ntA = (wave == 0) ? 0 : (wave + 1);
  f32x4 accA = zero4, accB = zero4;
  #pragma unroll
  for (int k0 = 0; k0 < 64; k0 += 32) {
    const short8 af = *(const short8*)&Hls[ln][k0 + g * 8];
    const short8 bA = *(const short8*)&WqkvT[(size_t)(ntA * 16 + ln) * 64 + k0 + g * 8];
    accA = __builtin_amdgcn_mfma_f32_16x16x32_bf16(af, bA, accA, 0, 0, 0);
    if (wave == 0) {
      const short8 bB = *(const short8*)&WqkvT[(size_t)(16 + ln) * 64 + k0 + g * 8];
      accB = __builtin_amdgcn_mfma_f32_16x16x32_bf16(af, bB, accB, 0, 0, 0);
    }
  }
  if (wave == 0) {
    const float b0 = (ln < 8) ? bq[ln] : bk[ln - 8];
    #pragma unroll
    for (int r = 0; r < 4; ++r) {
      const int m = q0 + 4 * g + r;
      const float v = accA[r] + b0;
      if (ln < 8) Qb[(size_t)m * 8 + ln] = bf16of(v);
      else        Kb[(size_t)m * 8 + (ln - 8)] = bf16of(v);
    }
    const int d = ln;
    const float bb = bv[d];
    uint2 o;
    o.x = bfpair(accB[0] + bb, accB[1] + bb);
    o.y = bfpair(accB[2] + bb, accB[3] + bb);
    *(uint2*)&VT[(size_t)d * 8192 + q0 + 4 * g] = o;
  } else {
    const int d = (ntA - 1) * 16 + ln;
    const float bb = bv[d];
    uint2 o;
    o.x = bfpair(accA[0] + bb, accA[1] + bb);
    o.y = bfpair(accA[2] + bb, accA[3] + bb);
    *(uint2*)&VT[(size_t)d * 8192 + q0 + 4 * g] = o;
  }
}

// ---------------- attention pass 1: qt=2, 8 waves x 32 q, SAME grid/j-split/Pnum ----------------
// grid 256 = 32 qg x 8 js (blockIdx = js*32 + qg). Per 128-j tile: 512 threads
// stage V(64x128, 2 chunks each) + K(128x8, tid<128) into padded dbuf LDS.
// Each V/K fragment read now feeds TWO q-tiles -> block LDS reads ~halved.
// Pnum layout identical to R13/R15 (row == q&255), epilogue unchanged.
__global__ __launch_bounds__(512) void attn_part_k(
    const ushort_t* __restrict__ Qb, const ushort_t* __restrict__ Kb,
    const ushort_t* __restrict__ VT, float* __restrict__ Pnum,
    float* __restrict__ Pden)
{
  const int tid = threadIdx.x;
  const int wave = tid >> 6, lane = tid & 63;
  const int m = lane & 15, g = lane >> 4;
  const int qg = blockIdx.x & 31, js = blockIdx.x >> 5;
  const int q0 = qg * 256 + wave * 32;
  const int j0 = js * 1024;
  const f32x4 zero4 = {0.f,0.f,0.f,0.f};

  __shared__ ushort_t Vls[2][64][136];
  __shared__ ushort_t Kls[2][128][12];

  const int vd0 = tid >> 4, vc0 = tid & 15;                 // chunks 0..511
  const int vd1 = (tid + 512) >> 4, vc1 = (tid + 512) & 15; // chunks 512..1023
  const bool isK = (tid < 128);

  short8 vr0 = {0,0,0,0,0,0,0,0}, vr1 = {0,0,0,0,0,0,0,0}, kreg = {0,0,0,0,0,0,0,0};
  auto LOAD = [&](int jb) {
    vr0 = *(const short8*)&VT[(size_t)vd0 * 8192 + jb + vc0 * 8];
    vr1 = *(const short8*)&VT[(size_t)vd1 * 8192 + jb + vc1 * 8];
    if (isK) kreg = *(const short8*)&Kb[(size_t)(jb + tid) * 8];
  };
  auto WRITE = [&](int cur) {
    *(short8*)&Vls[cur][vd0][vc0 * 8] = vr0;
    *(short8*)&Vls[cur][vd1][vc1 * 8] = vr1;
    if (isK) *(short8*)&Kls[cur][tid][0] = kreg;
  };

  short8 qf[2] = {{0,0,0,0,0,0,0,0},{0,0,0,0,0,0,0,0}};
  if (lane < 16) {
    qf[0] = *(const short8*)&Qb[(size_t)(q0 + m) * 8];
    qf[1] = *(const short8*)&Qb[(size_t)(q0 + 16 + m) * 8];
  }

  f32x4 acc[2][4];
  #pragma unroll
  for (int qt=0;qt<2;qt++)
    #pragma unroll
    for (int dt=0;dt<4;dt++) acc[qt][dt] = zero4;
  float lsum[2] = {0.f, 0.f};

  LOAD(j0);
  int cur = 0;
  for (int it = 0; it < 8; ++it) {
    WRITE(cur);
    __syncthreads();
    if (it + 1 < 8) LOAD(j0 + (it + 1) * 128);

    #pragma unroll
    for (int half = 0; half < 4; ++half) {
      short8 kf0 = {0,0,0,0,0,0,0,0}, kf1 = {0,0,0,0,0,0,0,0};
      if (lane < 16) {
        kf0 = *(const short8*)&Kls[cur][half*32 + m][0];
        kf1 = *(const short8*)&Kls[cur][half*32 + 16 + m][0];
      }
      short8 pf[2];
      #pragma unroll
      for (int qt = 0; qt < 2; ++qt) {
        const f32x4 s0 = __builtin_amdgcn_mfma_f32_16x16x32_bf16(kf0, qf[qt], zero4, 0,0,0);
        const f32x4 s1 = __builtin_amdgcn_mfma_f32_16x16x32_bf16(kf1, qf[qt], zero4, 0,0,0);
        const float e00 = __expf(s0[0]), e01 = __expf(s0[1]), e02 = __expf(s0[2]), e03 = __expf(s0[3]);
        const float e10 = __expf(s1[0]), e11 = __expf(s1[1]), e12 = __expf(s1[2]), e13 = __expf(s1[3]);
        lsum[qt] += ((e00+e01)+(e02+e03)) + ((e10+e11)+(e12+e13));
        unsigned X01 = bfpair(e00,e01), X23 = bfpair(e02,e03);
        unsigned Y01 = bfpair(e10,e11), Y23 = bfpair(e12,e13);
        permswap32(X01, Y01); permswap16(X01, Y01);
        permswap32(X23, Y23); permswap16(X23, Y23);
        union { unsigned u[4]; short8 s; } pfu;
        pfu.u[0] = X01;
        pfu.u[1] = X23;
        pfu.u[2] = Y01;
        pfu.u[3] = Y23;
        pf[qt] = pfu.s;
      }
      #pragma unroll
      for (int dt=0;dt<4;dt++) {
        const short8 vf = *(const short8*)&Vls[cur][dt*16 + m][half*32 + g * 8];
        acc[0][dt] = __builtin_amdgcn_mfma_f32_16x16x32_bf16(pf[0], vf, acc[0][dt], 0,0,0);
        acc[1][dt] = __builtin_amdgcn_mfma_f32_16x16x32_bf16(pf[1], vf, acc[1][dt], 0,0,0);
      }
    }
    cur ^= 1;
  }

  #pragma unroll
  for (int qt=0;qt<2;qt++) {
    lsum[qt] += __shfl_xor(lsum[qt], 16, 64);
    lsum[qt] += __shfl_xor(lsum[qt], 32, 64);
  }

  float* np = &Pnum[((size_t)blockIdx.x * 256 + wave * 32) * 64];
  #pragma unroll
  for (int qt=0;qt<2;qt++)
    #pragma unroll
    for (int dt=0;dt<4;dt++)
      #pragma unroll
      for (int r=0;r<4;r++)
        np[(size_t)(qt*16 + 4*g + r) * 64 + dt*16 + m] = acc[qt][dt][r];
  if (lane < 16) {
    Pden[(size_t)blockIdx.x * 256 + wave * 32 + m] = lsum[0];
    Pden[(size_t)blockIdx.x * 256 + wave * 32 + 16 + m] = lsum[1];
  }
}

// ---------------- fused epilogue (R13-verified) ----------------
__global__ __launch_bounds__(256) void epilogue_k(
    const float* __restrict__ Pnum, const float* __restrict__ Pden,
    const float* __restrict__ H3, const float* __restrict__ gamma,
    const ushort_t* __restrict__ Wa1t, const float* __restrict__ ba1,
    const float* __restrict__ Wa2, const float* __restrict__ ba2,
    float* __restrict__ pM, float* __restrict__ pS)
{
  const int wave = threadIdx.x >> 6, lane = threadIdx.x & 63;
  const int ln = lane & 15, g = lane >> 4;
  const int e = blockIdx.x;
  const int sub = e >> 5, qg = e & 31;
  const int q0 = qg * 256 + sub * 16;
  const f32x4 zero4 = {0.f, 0.f, 0.f, 0.f};

  __shared__ float Hals[16][68];
  __shared__ ushort_t Habls[16][72];
  __shared__ float scls[16];
  __shared__ float Ms[4][64];
  __shared__ float Ss[4];

  const float gm = gamma[0];
  #pragma unroll
  for (int rr = 0; rr < 4; ++rr) {
    const int r = wave * 4 + rr;
    const int q = q0 + r;
    const int qloc = q & 255;
    float num = 0.f, den = 0.f;
    #pragma unroll
    for (int js = 0; js < 8; ++js) {
      const size_t base = (size_t)(js * 32 + qg) * 256 + qloc;
      num += Pnum[base * 64 + lane];
      den += Pden[base];
    }
    const float hv = fmaf(gm, num / den, H3[(size_t)q * 64 + lane]);
    Hals[r][lane] = hv;
    Habls[r][lane] = bf16of(hv);
  }
  __syncthreads();

  f32x4 acc[4];
  #pragma unroll
  for (int nt = 0; nt < 4; ++nt) acc[nt] = zero4;
  #pragma unroll
  for (int k0 = 0; k0 < 64; k0 += 32) {
    const short8 af = *(const short8*)&Habls[ln][k0 + g * 8];
    #pragma unroll
    for (int nt = 0; nt < 4; ++nt) {
      const short8 bfr = *(const short8*)&Wa1t[(size_t)(nt * 16 + ln) * 64 + k0 + g * 8];
      acc[nt] = __builtin_amdgcn_mfma_f32_16x16x32_bf16(af, bfr, acc[nt], 0, 0, 0);
    }
  }
  #pragma unroll
  for (int r = 0; r < 4; ++r) {
    float s = 0.f;
    #pragma unroll
    for (int nt = 0; nt < 4; ++nt) {
      const int n = nt * 16 + ln;
      s += tanhf(acc[nt][r] + ba1[n]) * Wa2[n];
    }
    s += __shfl_xor(s, 1, 64); s += __shfl_xor(s, 2, 64);
    s += __shfl_xor(s, 4, 64); s += __shfl_xor(s, 8, 64);
    if (ln == 0) scls[4 * g + r] = s + ba2[0];
  }
  float macc = 0.f, se = 0.f;
  #pragma unroll
  for (int rr = 0; rr < 4; ++rr) {
    const int r = wave * 4 + rr;
    const float ee = __expf(scls[r]);
    se += ee;
    macc = fmaf(ee, Hals[r][lane], macc);
  }
  Ms[wave][lane] = macc;
  if (lane == 0) Ss[wave] = se;
  __syncthreads();
  if (wave == 0) {
    pM[(size_t)e * 64 + lane] = Ms[0][lane] + Ms[1][lane] + Ms[2][lane] + Ms[3][lane];
    if (lane == 0) pS[e] = Ss[0] + Ss[1] + Ss[2] + Ss[3];
  }
}

// ---------------- pooling stage 2 (R13-verified) ----------------
__global__ __launch_bounds__(1024) void pool2_k(
    const float* __restrict__ pM, const float* __restrict__ pS,
    const float* __restrict__ Wc, const float* __restrict__ bc,
    float* __restrict__ out)
{
  const int wave = threadIdx.x >> 6, lane = threadIdx.x & 63;
  __shared__ float Ms2[16][64];
  __shared__ float Ss2[16];
  float m_ = 0.f;
  #pragma unroll
  for (int i = 0; i < 32; ++i)
    m_ += pM[(size_t)(wave * 32 + i) * 64 + lane];
  Ms2[wave][lane] = m_;
  float s_ = (lane < 32) ? pS[wave * 32 + lane] : 0.f;
  s_ += __shfl_xor(s_, 1, 64);  s_ += __shfl_xor(s_, 2, 64);
  s_ += __shfl_xor(s_, 4, 64);  s_ += __shfl_xor(s_, 8, 64);
  s_ += __shfl_xor(s_, 16, 64); s_ += __shfl_xor(s_, 32, 64);
  if (lane == 0) Ss2[wave] = s_;
  __syncthreads();
  if (wave == 0) {
    float mm = 0.f, ss = 0.f;
    #pragma unroll
    for (int i = 0; i < 16; ++i) { mm += Ms2[i][lane]; ss += Ss2[i]; }
    const float Md = mm / ss;
    out[1 + lane] = Md;
    float yp = Md * Wc[lane];
    yp += __shfl_xor(yp, 1, 64);  yp += __shfl_xor(yp, 2, 64);
    yp += __shfl_xor(yp, 4, 64);  yp += __shfl_xor(yp, 8, 64);
    yp += __shfl_xor(yp, 16, 64); yp += __shfl_xor(yp, 32, 64);
    if (lane == 0) {
      float y = 1.f / (1.f + __expf(-(yp + bc[0])));
      y = fminf(fmaxf(y, 1e-5f), 1.f - 1e-5f);
      out[0] = y;
    }
  }
}

extern "C" void kernel_launch(void* const* d_in, const int* in_sizes, int n_in,
                              void* d_out, int out_size, void* d_ws, size_t ws_size,
                              hipStream_t stream)
{
  const float* x    = (const float*)d_in[0];
  const float* W1   = (const float*)d_in[1];
  const float* b1   = (const float*)d_in[2];
  const float* W2   = (const float*)d_in[3];
  const float* b2   = (const float*)d_in[4];
  const float* W3   = (const float*)d_in[5];
  const float* b3   = (const float*)d_in[6];
  const float* Wq   = (const float*)d_in[7];
  const float* bq   = (const float*)d_in[8];
  const float* Wk   = (const float*)d_in[9];
  const float* bk   = (const float*)d_in[10];
  const float* Wv   = (const float*)d_in[11];
  const float* bv   = (const float*)d_in[12];
  const float* gam  = (const float*)d_in[13];
  const float* Wa1  = (const float*)d_in[14];
  const float* ba1  = (const float*)d_in[15];
  const float* Wa2  = (const float*)d_in[16];
  const float* ba2  = (const float*)d_in[17];
  const float* Wc   = (const float*)d_in[18];
  const float* bc   = (const float*)d_in[19];
  float* out = (float*)d_out;

  char* w = (char*)d_ws;
  float* H3 = (float*)w;        w += (size_t)8192*64*4;
  float* pM = (float*)w;        w += 512*64*4;
  float* pS = (float*)w;        w += 512*4;
  float* Pnum = (float*)w;      w += (size_t)256*256*64*4;
  float* Pden = (float*)w;      w += (size_t)256*256*4;
  ushort_t* H1b = (ushort_t*)w; w += (size_t)8192*256*2;
  ushort_t* Qb  = (ushort_t*)w; w += (size_t)8192*8*2;
  ushort_t* Kb  = (ushort_t*)w; w += (size_t)8192*8*2;
  ushort_t* VT  = (ushort_t*)w; w += (size_t)64*8192*2;
  ushort_t* W1t = (ushort_t*)w; w += (size_t)256*1024*2;
  ushort_t* W2t = (ushort_t*)w; w += (size_t)128*256*2;
  ushort_t* W3t = (ushort_t*)w; w += (size_t)64*128*2;
  ushort_t* Wa1t= (ushort_t*)w; w += (size_t)64*64*2;
  ushort_t* Wqkv= (ushort_t*)w; w += (size_t)80*64*2;

  prep_all_k<<<301, 256, 0, stream>>>(W1, W1t, W2, W2t, W3, W3t, Wa1, Wa1t,
                                      Wq, Wk, Wv, Wqkv);
  gemm1_k<<<dim3(128, 4), 256, 0, stream>>>(x, W1t, b1, H1b);
  mlp23_qkv_k<<<512, 256, 0, stream>>>(H1b, W2t, b2, W3t, b3, Wqkv,
                                       bq, bk, bv, H3, Qb, Kb, VT);
  attn_part_k<<<256, 512, 0, stream>>>(Qb, Kb, VT, Pnum, Pden);
  epilogue_k<<<512, 256, 0, stream>>>(Pnum, Pden, H3, gam, Wa1t, ba1, Wa2, ba2, pM, pS);
  pool2_k<<<1, 1024, 0, stream>>>(pM, pS, Wc, bc, out);
}